// Round 10
// baseline (241.530 us; speedup 1.0000x reference)
//
#include <hip/hip_runtime.h>
#include <hip/hip_bf16.h>

#define NUM_C 1000
#define DIM   128
#define MM    64
#define BB    64
#define LL    512
#define NROWS (BB * LL)   // 32768

typedef unsigned short u16;
typedef unsigned int   u32;
typedef short bfrag __attribute__((ext_vector_type(8)));   // 8 bf16 (4 VGPRs)
typedef float f32x4 __attribute__((ext_vector_type(4)));   // MFMA acc

__device__ __forceinline__ float sigmoidf_fast(float x) { return 1.f / (1.f + __expf(-x)); }
__device__ __forceinline__ float tanhf_fast(float x) { return 1.f - 2.f / (__expf(2.f * x) + 1.f); }

__device__ __forceinline__ u16 f2bf(float x) {            // RNE f32->bf16 bits
    u32 u = __float_as_uint(x);
    return (u16)((u + 0x7FFFu + ((u >> 16) & 1u)) >> 16);
}
__device__ __forceinline__ float bf2f(u16 h) { return __uint_as_float(((u32)h) << 16); }

// ---------------------------------------------------------------------------
// Prep: bf16 hi/lo weights. weT/waT [n][k] (transposed), wfT [n][k] (transposed),
// mkT = Mk (already [m][k], no transpose).
// ---------------------------------------------------------------------------
__global__ __launch_bounds__(256) void kP(const float* __restrict__ We,
                                          const float* __restrict__ Wa,
                                          const float* __restrict__ Wf,
                                          const float* __restrict__ Mk,
                                          u16* weT_hi, u16* weT_lo,
                                          u16* waT_hi, u16* waT_lo,
                                          u16* wfT_hi, u16* wfT_lo,
                                          u16* mkT_hi, u16* mkT_lo) {
    int idx = blockIdx.x * 256 + threadIdx.x;   // 0..32767
    if (idx < 128 * 128) {
        int n = idx >> 7, k = idx & 127;
        float we = We[k * DIM + n];
        u16 h = f2bf(we);
        weT_hi[idx] = h; weT_lo[idx] = f2bf(we - bf2f(h));
        float wa = Wa[k * DIM + n];
        u16 h2 = f2bf(wa);
        waT_hi[idx] = h2; waT_lo[idx] = f2bf(wa - bf2f(h2));
    }
    if (idx < 64 * 128) {
        float mk = Mk[idx];
        u16 h = f2bf(mk);
        mkT_hi[idx] = h; mkT_lo[idx] = f2bf(mk - bf2f(h));
    }
    {
        int n = idx >> 8, k = idx & 255;
        float wf = Wf[k * DIM + n];
        u16 h = f2bf(wf);
        wfT_hi[idx] = h; wfT_lo[idx] = f2bf(wf - bf2f(h));
    }
}

// helper: split float8 chunk to bf16 hi/lo frags
__device__ __forceinline__ void split8(const float* src, bfrag& h, bfrag& l) {
    float4 f0 = *reinterpret_cast<const float4*>(src);
    float4 f1 = *reinterpret_cast<const float4*>(src + 4);
    float xs[8] = {f0.x, f0.y, f0.z, f0.w, f1.x, f1.y, f1.z, f1.w};
    #pragma unroll
    for (int j = 0; j < 8; ++j) {
        u16 hb = f2bf(xs[j]);
        h[j] = (short)hb;
        l[j] = (short)f2bf(xs[j] - bf2f(hb));
    }
}

// ---------------------------------------------------------------------------
// Kernel A (MFMA): w[row][m] = softmax_m(Ek[q[row]] . Mk[m]); 64 rows/block.
// Stage k bf16 hi/lo in LDS; wave wv owns m-tile [wv*16, wv*16+16).
// Softmax without max-subtract (scores bounded; exp safe in f32).
// ---------------------------------------------------------------------------
__global__ __launch_bounds__(256) void kA(const int* __restrict__ q,
                                          const float* __restrict__ Ek,
                                          const u16* __restrict__ mkT_hi,
                                          const u16* __restrict__ mkT_lo,
                                          float* __restrict__ w_out) {
    __shared__ __align__(16) u16 khi[4][16][136];
    __shared__ __align__(16) u16 klo[4][16][136];
    __shared__ float slab[4][64];
    const int tid = threadIdx.x;
    const int base = blockIdx.x * 64;

    {   // stage
        const int row_l = tid >> 2;
        const int rts = row_l >> 4, ms = row_l & 15;
        const int d0 = (tid & 3) * 32;
        const float* src = Ek + (size_t)q[base + row_l] * DIM + d0;
        #pragma unroll
        for (int c8 = 0; c8 < 4; ++c8) {
            bfrag h, l;
            split8(src + c8 * 8, h, l);
            *reinterpret_cast<bfrag*>(&khi[rts][ms][d0 + c8 * 8]) = h;
            *reinterpret_cast<bfrag*>(&klo[rts][ms][d0 + c8 * 8]) = l;
        }
    }
    __syncthreads();

    const int lane = tid & 63;
    const int wv = tid >> 6;
    const int nloc = lane & 15;
    const int quad = lane >> 4;
    const int n = wv * 16 + nloc;      // m index

    bfrag Bh[4], Bl[4];
    #pragma unroll
    for (int kc = 0; kc < 4; ++kc) {
        const int ko = kc * 32 + quad * 8;
        Bh[kc] = *reinterpret_cast<const bfrag*>(mkT_hi + n * DIM + ko);
        Bl[kc] = *reinterpret_cast<const bfrag*>(mkT_lo + n * DIM + ko);
    }

    f32x4 acc[4];
    #pragma unroll
    for (int t = 0; t < 4; ++t) acc[t] = 0.f;

    #pragma unroll
    for (int rt = 0; rt < 4; ++rt) {
        #pragma unroll
        for (int kc = 0; kc < 4; ++kc) {
            const int ko = kc * 32 + quad * 8;
            bfrag Ah = *reinterpret_cast<const bfrag*>(&khi[rt][nloc][ko]);
            bfrag Al = *reinterpret_cast<const bfrag*>(&klo[rt][nloc][ko]);
            acc[rt] = __builtin_amdgcn_mfma_f32_16x16x32_bf16(Ah, Bh[kc], acc[rt], 0, 0, 0);
            acc[rt] = __builtin_amdgcn_mfma_f32_16x16x32_bf16(Ah, Bl[kc], acc[rt], 0, 0, 0);
            acc[rt] = __builtin_amdgcn_mfma_f32_16x16x32_bf16(Al, Bh[kc], acc[rt], 0, 0, 0);
        }
    }

    // exp + partial row-sum over this wave's 16 m (lanes nloc), stash in slab
    float ex[4][4];
    #pragma unroll
    for (int rt = 0; rt < 4; ++rt) {
        #pragma unroll
        for (int rg = 0; rg < 4; ++rg) {
            float e = __expf(acc[rt][rg]);
            ex[rt][rg] = e;
            float s = e;
            s += __shfl_xor(s, 1);
            s += __shfl_xor(s, 2);
            s += __shfl_xor(s, 4);
            s += __shfl_xor(s, 8);
            if (nloc == 0) slab[wv][rt * 16 + quad * 4 + rg] = s;
        }
    }
    __syncthreads();

    #pragma unroll
    for (int rt = 0; rt < 4; ++rt) {
        #pragma unroll
        for (int rg = 0; rg < 4; ++rg) {
            const int row = rt * 16 + quad * 4 + rg;
            float tot = slab[0][row] + slab[1][row] + slab[2][row] + slab[3][row];
            w_out[(size_t)(base + row) * MM + n] = ex[rt][rg] / tot;
        }
    }
}

// ---------------------------------------------------------------------------
// Kernel B (MFMA): e/a, written interleaved as float2 ea_buf[row*DIM+d].
// ---------------------------------------------------------------------------
__global__ __launch_bounds__(256) void kB(const int* __restrict__ q,
                                          const int* __restrict__ r,
                                          const float* __restrict__ Ev,
                                          const u16* __restrict__ weT_hi, const u16* __restrict__ weT_lo,
                                          const u16* __restrict__ waT_hi, const u16* __restrict__ waT_lo,
                                          const float* __restrict__ be, const float* __restrict__ ba,
                                          float2* __restrict__ ea_out) {
    __shared__ __align__(16) u16 vhi[4][16][136];
    __shared__ __align__(16) u16 vlo[4][16][136];
    __shared__ float slab[4][16][DIM];                 // 32 KB: [h][rowtile-row][n]
    const int tid = threadIdx.x;
    const int base = blockIdx.x * 64;

    {   // stage
        const int row_l = tid >> 2;
        const int rts = row_l >> 4, ms = row_l & 15;
        const int d0 = (tid & 3) * 32;
        const int row = base + row_l;
        const int x = q[row] + NUM_C * r[row];
        const float* src = Ev + (size_t)x * DIM + d0;
        #pragma unroll
        for (int c8 = 0; c8 < 4; ++c8) {
            bfrag h, l;
            split8(src + c8 * 8, h, l);
            *reinterpret_cast<bfrag*>(&vhi[rts][ms][d0 + c8 * 8]) = h;
            *reinterpret_cast<bfrag*>(&vlo[rts][ms][d0 + c8 * 8]) = l;
        }
    }
    __syncthreads();

    const int lane = tid & 63;
    const int wv = tid >> 6;
    const int nloc = lane & 15;
    const int quad = lane >> 4;

    #pragma unroll
    for (int dt = 0; dt < 2; ++dt) {
        const int n = (wv * 2 + dt) * 16 + nloc;
        bfrag Beh[4], Bel[4], Bah[4], Bal[4];
        #pragma unroll
        for (int kc = 0; kc < 4; ++kc) {
            const int ko = kc * 32 + quad * 8;
            Beh[kc] = *reinterpret_cast<const bfrag*>(weT_hi + n * DIM + ko);
            Bel[kc] = *reinterpret_cast<const bfrag*>(weT_lo + n * DIM + ko);
            Bah[kc] = *reinterpret_cast<const bfrag*>(waT_hi + n * DIM + ko);
            Bal[kc] = *reinterpret_cast<const bfrag*>(waT_lo + n * DIM + ko);
        }
        f32x4 acc_e[4], acc_a[4];
        #pragma unroll
        for (int t = 0; t < 4; ++t) { acc_e[t] = 0.f; acc_a[t] = 0.f; }

        #pragma unroll
        for (int rt = 0; rt < 4; ++rt) {
            #pragma unroll
            for (int kc = 0; kc < 4; ++kc) {
                const int ko = kc * 32 + quad * 8;
                bfrag Ah = *reinterpret_cast<const bfrag*>(&vhi[rt][nloc][ko]);
                bfrag Al = *reinterpret_cast<const bfrag*>(&vlo[rt][nloc][ko]);
                acc_e[rt] = __builtin_amdgcn_mfma_f32_16x16x32_bf16(Ah, Beh[kc], acc_e[rt], 0, 0, 0);
                acc_a[rt] = __builtin_amdgcn_mfma_f32_16x16x32_bf16(Ah, Bah[kc], acc_a[rt], 0, 0, 0);
                acc_e[rt] = __builtin_amdgcn_mfma_f32_16x16x32_bf16(Ah, Bel[kc], acc_e[rt], 0, 0, 0);
                acc_a[rt] = __builtin_amdgcn_mfma_f32_16x16x32_bf16(Ah, Bal[kc], acc_a[rt], 0, 0, 0);
                acc_e[rt] = __builtin_amdgcn_mfma_f32_16x16x32_bf16(Al, Beh[kc], acc_e[rt], 0, 0, 0);
                acc_a[rt] = __builtin_amdgcn_mfma_f32_16x16x32_bf16(Al, Bah[kc], acc_a[rt], 0, 0, 0);
            }
        }
        const float bev = be[n], bav = ba[n];
        #pragma unroll
        for (int rt = 0; rt < 4; ++rt) {
            #pragma unroll
            for (int rg = 0; rg < 4; ++rg) {
                const int row = base + rt * 16 + quad * 4 + rg;
                float2 ea;
                ea.x = sigmoidf_fast(acc_e[rt][rg] + bev);
                ea.y = tanhf_fast(acc_a[rt][rg] + bav);
                ea_out[(size_t)row * DIM + n] = ea;
            }
        }
    }
}

// ---------------------------------------------------------------------------
// Kernel C: scan, all-m per block. Grid (ds=4, b=64) = 256 blocks, 512 thr.
// Thread: p = tid&15 owns 4 m (m0=p*4); dl = tid>>4 -> d = ds*32+dl.
// e/a read once (d-partitioned), w x4. In-wave 16-lane m-reduce ->
// DIRECT write to read_buf (no partial buffers).
// ---------------------------------------------------------------------------
__device__ __forceinline__ void kc_load_tile(const float2* eap, int c, float2 (&eaR)[16]) {
    if (c < LL / 16) {
        #pragma unroll
        for (int u = 0; u < 16; ++u)
            eaR[u] = eap[(size_t)(c * 16 + u) * DIM];
    }
}

__device__ __forceinline__ void kc_scan_tile(int c, int p, float (&Mv)[4],
                                             const float2 (&eaR)[16],
                                             float4 (&wR)[8],
                                             const float* wp, float* rp) {
    #pragma unroll
    for (int u = 0; u < 16; ++u) {
        const int t = c * 16 + u;
        const int slot = u & 7;
        float4 w4 = wR[slot];
        if (t + 8 < LL)
            wR[slot] = *reinterpret_cast<const float4*>(wp + (size_t)(t + 8) * MM);
        float e_c = eaR[u].x, a_c = eaR[u].y;
        float wv[4] = {w4.x, w4.y, w4.z, w4.w};
        float part = 0.f;
        #pragma unroll
        for (int j = 0; j < 4; ++j) {
            float old = Mv[j];
            part = fmaf(wv[j], old, part);             // read BEFORE update
            Mv[j] = fmaf(wv[j], fmaf(-old, e_c, a_c), old);
        }
        part += __shfl_xor(part, 1);
        part += __shfl_xor(part, 2);
        part += __shfl_xor(part, 4);
        part += __shfl_xor(part, 8);
        if (p == 0) rp[(size_t)t * DIM] = part;
    }
}

__global__ __launch_bounds__(512) void kC(const float* __restrict__ Mv0,
                                          const float* __restrict__ w_in,
                                          const float2* __restrict__ ea_in,
                                          float* __restrict__ read_buf) {
    const int tid = threadIdx.x;
    const int p = tid & 15;
    const int dl = tid >> 4;
    const int ds = blockIdx.x, b = blockIdx.y;
    const int d = ds * 32 + dl;
    const int m0 = p * 4;

    float Mv[4];
    #pragma unroll
    for (int j = 0; j < 4; ++j)
        Mv[j] = Mv0[(m0 + j) * DIM + d];

    const float*  wp  = w_in  + (size_t)b * LL * MM + m0;
    const float2* eap = ea_in + (size_t)b * LL * DIM + d;
    float*        rp  = read_buf + (size_t)b * LL * DIM + d;

    float2 eaR0[16], eaR1[16];
    float4 wR[8];

    kc_load_tile(eap, 0, eaR0);
    #pragma unroll
    for (int u = 0; u < 8; ++u)
        wR[u] = *reinterpret_cast<const float4*>(wp + (size_t)u * MM);

    for (int c = 0; c < LL / 16; c += 2) {
        kc_load_tile(eap, c + 1, eaR1);
        kc_scan_tile(c, p, Mv, eaR0, wR, wp, rp);
        kc_load_tile(eap, c + 2, eaR0);
        kc_scan_tile(c + 1, p, Mv, eaR1, wR, wp, rp);
    }
}

// ---------------------------------------------------------------------------
// Kernel D (MFMA): f = tanh([read,k]@Wf+bf); p = sigmoid(f@Wp+bp). 64 rows/blk.
// ---------------------------------------------------------------------------
__global__ __launch_bounds__(256) void kD(const int* __restrict__ q,
                                          const float* __restrict__ Ek,
                                          const u16* __restrict__ wfT_hi, const u16* __restrict__ wfT_lo,
                                          const float* __restrict__ bfv,
                                          const float* __restrict__ Wp, const float* __restrict__ bp,
                                          const float* __restrict__ read_buf,
                                          float* __restrict__ out) {
    __shared__ __align__(16) u16 xhi[4][16][264];
    __shared__ __align__(16) u16 xlo[4][16][264];
    __shared__ float sred[64][4];
    const int tid = threadIdx.x;
    const int base = blockIdx.x * 64;
    const int row_l = tid >> 2;
    const int rts = row_l >> 4, ms = row_l & 15;
    const int d0 = (tid & 3) * 32;
    const int row = base + row_l;

    {   // x[:, 0:128) = read_buf
        const float* src = read_buf + (size_t)row * DIM + d0;
        #pragma unroll
        for (int c8 = 0; c8 < 4; ++c8) {
            bfrag h, l;
            split8(src + c8 * 8, h, l);
            *reinterpret_cast<bfrag*>(&xhi[rts][ms][d0 + c8 * 8]) = h;
            *reinterpret_cast<bfrag*>(&xlo[rts][ms][d0 + c8 * 8]) = l;
        }
    }
    {   // x[:, 128:256) = Ek[q[row]]
        const float* src = Ek + (size_t)q[row] * DIM + d0;
        #pragma unroll
        for (int c8 = 0; c8 < 4; ++c8) {
            bfrag h, l;
            split8(src + c8 * 8, h, l);
            *reinterpret_cast<bfrag*>(&xhi[rts][ms][128 + d0 + c8 * 8]) = h;
            *reinterpret_cast<bfrag*>(&xlo[rts][ms][128 + d0 + c8 * 8]) = l;
        }
    }
    __syncthreads();

    const int lane = tid & 63;
    const int wv = tid >> 6;
    const int nloc = lane & 15;
    const int quad = lane >> 4;
    float* fbuf = reinterpret_cast<float*>(&xhi[0][0][0]);   // overlay after sync

    f32x4 acc[2][4];
    #pragma unroll
    for (int dt = 0; dt < 2; ++dt)
        #pragma unroll
        for (int t = 0; t < 4; ++t) acc[dt][t] = 0.f;

    #pragma unroll
    for (int dt = 0; dt < 2; ++dt) {
        const int n = (wv * 2 + dt) * 16 + nloc;
        bfrag Bh[8], Bl[8];
        #pragma unroll
        for (int kc = 0; kc < 8; ++kc) {
            const int ko = kc * 32 + quad * 8;
            Bh[kc] = *reinterpret_cast<const bfrag*>(wfT_hi + n * 256 + ko);
            Bl[kc] = *reinterpret_cast<const bfrag*>(wfT_lo + n * 256 + ko);
        }
        #pragma unroll
        for (int rt = 0; rt < 4; ++rt) {
            #pragma unroll
            for (int kc = 0; kc < 8; ++kc) {
                const int ko = kc * 32 + quad * 8;
                bfrag Ah = *reinterpret_cast<const bfrag*>(&xhi[rt][nloc][ko]);
                bfrag Al = *reinterpret_cast<const bfrag*>(&xlo[rt][nloc][ko]);
                acc[dt][rt] = __builtin_amdgcn_mfma_f32_16x16x32_bf16(Ah, Bh[kc], acc[dt][rt], 0, 0, 0);
                acc[dt][rt] = __builtin_amdgcn_mfma_f32_16x16x32_bf16(Ah, Bl[kc], acc[dt][rt], 0, 0, 0);
                acc[dt][rt] = __builtin_amdgcn_mfma_f32_16x16x32_bf16(Al, Bh[kc], acc[dt][rt], 0, 0, 0);
            }
        }
    }
    __syncthreads();   // LDS x reads done before fbuf overlay

    #pragma unroll
    for (int dt = 0; dt < 2; ++dt) {
        const int n = (wv * 2 + dt) * 16 + nloc;
        const float bfn = bfv[n], wpn = Wp[n];
        #pragma unroll
        for (int rt = 0; rt < 4; ++rt)
            #pragma unroll
            for (int rg = 0; rg < 4; ++rg)
                fbuf[(rt * 16 + quad * 4 + rg) * 132 + n] = tanhf_fast(acc[dt][rt][rg] + bfn) * wpn;
    }
    __syncthreads();

    {
        float s = 0.f;
        const int c = tid & 3;
        #pragma unroll
        for (int k = 0; k < 32; ++k) s += fbuf[row_l * 132 + c * 32 + k];
        sred[row_l][c] = s;
    }
    __syncthreads();
    if (tid < 64)
        out[base + tid] = sigmoidf_fast(sred[tid][0] + sred[tid][1] + sred[tid][2] + sred[tid][3] + bp[0]);
}

// ---------------------------------------------------------------------------
extern "C" void kernel_launch(void* const* d_in, const int* in_sizes, int n_in,
                              void* d_out, int out_size, void* d_ws, size_t ws_size,
                              hipStream_t stream) {
    const int*   q   = (const int*)d_in[0];
    const int*   r   = (const int*)d_in[1];
    const float* Ek  = (const float*)d_in[2];
    const float* Ev  = (const float*)d_in[3];
    const float* Mk  = (const float*)d_in[4];
    const float* Mv0 = (const float*)d_in[5];
    const float* We  = (const float*)d_in[6];
    const float* be  = (const float*)d_in[7];
    const float* Wa  = (const float*)d_in[8];
    const float* ba  = (const float*)d_in[9];
    const float* Wf  = (const float*)d_in[10];
    const float* bfv = (const float*)d_in[11];
    const float* Wp  = (const float*)d_in[12];
    const float* bp  = (const float*)d_in[13];
    float* out = (float*)d_out;

    float*  ws     = (float*)d_ws;
    float*  w_buf  = ws;                                  // 8 MB
    float2* ea_buf = (float2*)(w_buf + (size_t)NROWS * MM);   // 32 MB
    float*  rd_buf = (float*)(ea_buf + (size_t)NROWS * DIM);  // 16 MB

    // prepped bf16 weights at the END of ws (288 KB)
    size_t prep_off = (ws_size - (size_t)294912) & ~(size_t)255;
    u16* weT_hi = (u16*)((char*)d_ws + prep_off);
    u16* weT_lo = weT_hi + 16384;
    u16* waT_hi = weT_lo + 16384;
    u16* waT_lo = waT_hi + 16384;
    u16* wfT_hi = waT_lo + 16384;
    u16* wfT_lo = wfT_hi + 32768;
    u16* mkT_hi = wfT_lo + 32768;
    u16* mkT_lo = mkT_hi + 8192;

    kP<<<dim3(128), 256, 0, stream>>>(We, Wa, Wf, Mk, weT_hi, weT_lo, waT_hi, waT_lo,
                                      wfT_hi, wfT_lo, mkT_hi, mkT_lo);
    kA<<<dim3(NROWS / 64), 256, 0, stream>>>(q, Ek, mkT_hi, mkT_lo, w_buf);
    kB<<<dim3(NROWS / 64), 256, 0, stream>>>(q, r, Ev, weT_hi, weT_lo, waT_hi, waT_lo,
                                             be, ba, ea_buf);
    kC<<<dim3(4, BB), 512, 0, stream>>>(Mv0, w_buf, ea_buf, rd_buf);
    kD<<<dim3(NROWS / 64), 256, 0, stream>>>(q, Ek, wfT_hi, wfT_lo, bfv, Wp, bp, rd_buf, out);
}

// Round 11
// 200.288 us; speedup vs baseline: 1.2059x; 1.2059x over previous
//
#include <hip/hip_runtime.h>
#include <hip/hip_bf16.h>

#define NUM_C 1000
#define DIM   128
#define MM    64
#define BB    64
#define LL    512
#define NROWS (BB * LL)   // 32768

typedef unsigned short u16;
typedef unsigned int   u32;
typedef short bfrag __attribute__((ext_vector_type(8)));   // 8 bf16 (4 VGPRs)
typedef float f32x4 __attribute__((ext_vector_type(4)));   // MFMA acc

__device__ __forceinline__ float sigmoidf_fast(float x) { return 1.f / (1.f + __expf(-x)); }
__device__ __forceinline__ float tanhf_fast(float x) { return 1.f - 2.f / (__expf(2.f * x) + 1.f); }

__device__ __forceinline__ u16 f2bf(float x) {            // RNE f32->bf16 bits
    u32 u = __float_as_uint(x);
    return (u16)((u + 0x7FFFu + ((u >> 16) & 1u)) >> 16);
}
__device__ __forceinline__ float bf2f(u16 h) { return __uint_as_float(((u32)h) << 16); }

// DPP quad_perm swaps (VALU-only, verified rounds 5-10)
__device__ __forceinline__ float quad_swap1(float x) {
    return __int_as_float(__builtin_amdgcn_mov_dpp(__float_as_int(x), 0xB1, 0xF, 0xF, true));
}
__device__ __forceinline__ float quad_swap2(float x) {
    return __int_as_float(__builtin_amdgcn_mov_dpp(__float_as_int(x), 0x4E, 0xF, 0xF, true));
}
// xor-4 lane swap via ds_swizzle bitmode: offset = (4<<10)|0x1F
__device__ __forceinline__ float swz_xor4(float x) {
    return __int_as_float(__builtin_amdgcn_ds_swizzle(__float_as_int(x), 0x101F));
}

// async global->LDS DMA, 16B per lane, LDS dest = base + lane*16
__device__ __forceinline__ void ld16(const void* g, void* l) {
    __builtin_amdgcn_global_load_lds(
        (const __attribute__((address_space(1))) unsigned int*)g,
        (__attribute__((address_space(3))) unsigned int*)l, 16, 0, 0);
}

// ---------------------------------------------------------------------------
// Prep: bf16 hi/lo weights. weT/waT [n][k] (transposed), wfT [n][k] (transposed),
// mkT = Mk (already [m][k], no transpose).
// ---------------------------------------------------------------------------
__global__ __launch_bounds__(256) void kP(const float* __restrict__ We,
                                          const float* __restrict__ Wa,
                                          const float* __restrict__ Wf,
                                          const float* __restrict__ Mk,
                                          u16* weT_hi, u16* weT_lo,
                                          u16* waT_hi, u16* waT_lo,
                                          u16* wfT_hi, u16* wfT_lo,
                                          u16* mkT_hi, u16* mkT_lo) {
    int idx = blockIdx.x * 256 + threadIdx.x;   // 0..32767
    if (idx < 128 * 128) {
        int n = idx >> 7, k = idx & 127;
        float we = We[k * DIM + n];
        u16 h = f2bf(we);
        weT_hi[idx] = h; weT_lo[idx] = f2bf(we - bf2f(h));
        float wa = Wa[k * DIM + n];
        u16 h2 = f2bf(wa);
        waT_hi[idx] = h2; waT_lo[idx] = f2bf(wa - bf2f(h2));
    }
    if (idx < 64 * 128) {
        float mk = Mk[idx];
        u16 h = f2bf(mk);
        mkT_hi[idx] = h; mkT_lo[idx] = f2bf(mk - bf2f(h));
    }
    {
        int n = idx >> 8, k = idx & 255;
        float wf = Wf[k * DIM + n];
        u16 h = f2bf(wf);
        wfT_hi[idx] = h; wfT_lo[idx] = f2bf(wf - bf2f(h));
    }
}

// helper: split float8 chunk to bf16 hi/lo frags
__device__ __forceinline__ void split8(const float* src, bfrag& h, bfrag& l) {
    float4 f0 = *reinterpret_cast<const float4*>(src);
    float4 f1 = *reinterpret_cast<const float4*>(src + 4);
    float xs[8] = {f0.x, f0.y, f0.z, f0.w, f1.x, f1.y, f1.z, f1.w};
    #pragma unroll
    for (int j = 0; j < 8; ++j) {
        u16 hb = f2bf(xs[j]);
        h[j] = (short)hb;
        l[j] = (short)f2bf(xs[j] - bf2f(hb));
    }
}

// ---------------------------------------------------------------------------
// Kernel A (MFMA): w[row][m] = softmax_m(Ek[q[row]] . Mk[m]); 64 rows/block.
// ---------------------------------------------------------------------------
__global__ __launch_bounds__(256) void kA(const int* __restrict__ q,
                                          const float* __restrict__ Ek,
                                          const u16* __restrict__ mkT_hi,
                                          const u16* __restrict__ mkT_lo,
                                          float* __restrict__ w_out) {
    __shared__ __align__(16) u16 khi[4][16][136];
    __shared__ __align__(16) u16 klo[4][16][136];
    __shared__ float slab[4][64];
    const int tid = threadIdx.x;
    const int base = blockIdx.x * 64;

    {   // stage
        const int row_l = tid >> 2;
        const int rts = row_l >> 4, ms = row_l & 15;
        const int d0 = (tid & 3) * 32;
        const float* src = Ek + (size_t)q[base + row_l] * DIM + d0;
        #pragma unroll
        for (int c8 = 0; c8 < 4; ++c8) {
            bfrag h, l;
            split8(src + c8 * 8, h, l);
            *reinterpret_cast<bfrag*>(&khi[rts][ms][d0 + c8 * 8]) = h;
            *reinterpret_cast<bfrag*>(&klo[rts][ms][d0 + c8 * 8]) = l;
        }
    }
    __syncthreads();

    const int lane = tid & 63;
    const int wv = tid >> 6;
    const int nloc = lane & 15;
    const int quad = lane >> 4;
    const int n = wv * 16 + nloc;      // m index

    bfrag Bh[4], Bl[4];
    #pragma unroll
    for (int kc = 0; kc < 4; ++kc) {
        const int ko = kc * 32 + quad * 8;
        Bh[kc] = *reinterpret_cast<const bfrag*>(mkT_hi + n * DIM + ko);
        Bl[kc] = *reinterpret_cast<const bfrag*>(mkT_lo + n * DIM + ko);
    }

    f32x4 acc[4];
    #pragma unroll
    for (int t = 0; t < 4; ++t) acc[t] = 0.f;

    #pragma unroll
    for (int rt = 0; rt < 4; ++rt) {
        #pragma unroll
        for (int kc = 0; kc < 4; ++kc) {
            const int ko = kc * 32 + quad * 8;
            bfrag Ah = *reinterpret_cast<const bfrag*>(&khi[rt][nloc][ko]);
            bfrag Al = *reinterpret_cast<const bfrag*>(&klo[rt][nloc][ko]);
            acc[rt] = __builtin_amdgcn_mfma_f32_16x16x32_bf16(Ah, Bh[kc], acc[rt], 0, 0, 0);
            acc[rt] = __builtin_amdgcn_mfma_f32_16x16x32_bf16(Ah, Bl[kc], acc[rt], 0, 0, 0);
            acc[rt] = __builtin_amdgcn_mfma_f32_16x16x32_bf16(Al, Bh[kc], acc[rt], 0, 0, 0);
        }
    }

    float ex[4][4];
    #pragma unroll
    for (int rt = 0; rt < 4; ++rt) {
        #pragma unroll
        for (int rg = 0; rg < 4; ++rg) {
            float e = __expf(acc[rt][rg]);
            ex[rt][rg] = e;
            float s = e;
            s += __shfl_xor(s, 1);
            s += __shfl_xor(s, 2);
            s += __shfl_xor(s, 4);
            s += __shfl_xor(s, 8);
            if (nloc == 0) slab[wv][rt * 16 + quad * 4 + rg] = s;
        }
    }
    __syncthreads();

    #pragma unroll
    for (int rt = 0; rt < 4; ++rt) {
        #pragma unroll
        for (int rg = 0; rg < 4; ++rg) {
            const int row = rt * 16 + quad * 4 + rg;
            float tot = slab[0][row] + slab[1][row] + slab[2][row] + slab[3][row];
            w_out[(size_t)(base + row) * MM + n] = ex[rt][rg] / tot;
        }
    }
}

// ---------------------------------------------------------------------------
// Kernel B (MFMA): e/a, written interleaved as float2 ea_buf[row*DIM+d].
// ---------------------------------------------------------------------------
__global__ __launch_bounds__(256) void kB(const int* __restrict__ q,
                                          const int* __restrict__ r,
                                          const float* __restrict__ Ev,
                                          const u16* __restrict__ weT_hi, const u16* __restrict__ weT_lo,
                                          const u16* __restrict__ waT_hi, const u16* __restrict__ waT_lo,
                                          const float* __restrict__ be, const float* __restrict__ ba,
                                          float2* __restrict__ ea_out) {
    __shared__ __align__(16) u16 vhi[4][16][136];
    __shared__ __align__(16) u16 vlo[4][16][136];
    const int tid = threadIdx.x;
    const int base = blockIdx.x * 64;

    {   // stage
        const int row_l = tid >> 2;
        const int rts = row_l >> 4, ms = row_l & 15;
        const int d0 = (tid & 3) * 32;
        const int row = base + row_l;
        const int x = q[row] + NUM_C * r[row];
        const float* src = Ev + (size_t)x * DIM + d0;
        #pragma unroll
        for (int c8 = 0; c8 < 4; ++c8) {
            bfrag h, l;
            split8(src + c8 * 8, h, l);
            *reinterpret_cast<bfrag*>(&vhi[rts][ms][d0 + c8 * 8]) = h;
            *reinterpret_cast<bfrag*>(&vlo[rts][ms][d0 + c8 * 8]) = l;
        }
    }
    __syncthreads();

    const int lane = tid & 63;
    const int wv = tid >> 6;
    const int nloc = lane & 15;
    const int quad = lane >> 4;

    #pragma unroll
    for (int dt = 0; dt < 2; ++dt) {
        const int n = (wv * 2 + dt) * 16 + nloc;
        bfrag Beh[4], Bel[4], Bah[4], Bal[4];
        #pragma unroll
        for (int kc = 0; kc < 4; ++kc) {
            const int ko = kc * 32 + quad * 8;
            Beh[kc] = *reinterpret_cast<const bfrag*>(weT_hi + n * DIM + ko);
            Bel[kc] = *reinterpret_cast<const bfrag*>(weT_lo + n * DIM + ko);
            Bah[kc] = *reinterpret_cast<const bfrag*>(waT_hi + n * DIM + ko);
            Bal[kc] = *reinterpret_cast<const bfrag*>(waT_lo + n * DIM + ko);
        }
        f32x4 acc_e[4], acc_a[4];
        #pragma unroll
        for (int t = 0; t < 4; ++t) { acc_e[t] = 0.f; acc_a[t] = 0.f; }

        #pragma unroll
        for (int rt = 0; rt < 4; ++rt) {
            #pragma unroll
            for (int kc = 0; kc < 4; ++kc) {
                const int ko = kc * 32 + quad * 8;
                bfrag Ah = *reinterpret_cast<const bfrag*>(&vhi[rt][nloc][ko]);
                bfrag Al = *reinterpret_cast<const bfrag*>(&vlo[rt][nloc][ko]);
                acc_e[rt] = __builtin_amdgcn_mfma_f32_16x16x32_bf16(Ah, Beh[kc], acc_e[rt], 0, 0, 0);
                acc_a[rt] = __builtin_amdgcn_mfma_f32_16x16x32_bf16(Ah, Bah[kc], acc_a[rt], 0, 0, 0);
                acc_e[rt] = __builtin_amdgcn_mfma_f32_16x16x32_bf16(Ah, Bel[kc], acc_e[rt], 0, 0, 0);
                acc_a[rt] = __builtin_amdgcn_mfma_f32_16x16x32_bf16(Ah, Bal[kc], acc_a[rt], 0, 0, 0);
                acc_e[rt] = __builtin_amdgcn_mfma_f32_16x16x32_bf16(Al, Beh[kc], acc_e[rt], 0, 0, 0);
                acc_a[rt] = __builtin_amdgcn_mfma_f32_16x16x32_bf16(Al, Bah[kc], acc_a[rt], 0, 0, 0);
            }
        }
        const float bev = be[n], bav = ba[n];
        #pragma unroll
        for (int rt = 0; rt < 4; ++rt) {
            #pragma unroll
            for (int rg = 0; rg < 4; ++rg) {
                const int row = base + rt * 16 + quad * 4 + rg;
                float2 ea;
                ea.x = sigmoidf_fast(acc_e[rt][rg] + bev);
                ea.y = tanhf_fast(acc_a[rt][rg] + bav);
                ea_out[(size_t)row * DIM + n] = ea;
            }
        }
    }
}

// ---------------------------------------------------------------------------
// Kernel C: scan with async-DMA LDS tiles. Grid (ds=4, b=64) = 256 blocks,
// 256 thr. Thread: p = tid&7 owns 8 m (m0=p*8); dl = tid>>3 -> d = ds*32+dl.
// Tiles of T=32 steps double-buffered: w 8KB + ea 8KB per buffer, filled by
// global_load_lds (async; issued for tile c+1 right after the tile-c barrier
// so ~2700 cyc of scan covers the ~900 cyc DMA latency). Low VGPR count lets
// the compiler pipeline ds_reads across unrolled steps (fine lgkmcnt).
// Reduce over 8 lanes: quad_swap1 + quad_swap2 (DPP) + ds_swizzle xor4.
// Direct write to read_buf (all m in-block; no partial buffers).
// ---------------------------------------------------------------------------
__device__ __forceinline__ void scan32(const float* wb, const float2* eab,
                                       int m0, int dl, int p, int t0,
                                       float (&Mv)[8], float* rp) {
    #pragma unroll
    for (int u = 0; u < 32; ++u) {
        float4 w0 = *reinterpret_cast<const float4*>(wb + u * 64 + m0);
        float4 w1 = *reinterpret_cast<const float4*>(wb + u * 64 + m0 + 4);
        float2 ea = eab[u * 32 + dl];
        float wv[8] = {w0.x, w0.y, w0.z, w0.w, w1.x, w1.y, w1.z, w1.w};
        float e_c = ea.x, a_c = ea.y;
        float p0 = 0.f, p1 = 0.f;
        #pragma unroll
        for (int j = 0; j < 4; ++j) {
            float old = Mv[j];
            p0 = fmaf(wv[j], old, p0);                       // read BEFORE update
            Mv[j] = fmaf(wv[j], fmaf(-old, e_c, a_c), old);
        }
        #pragma unroll
        for (int j = 4; j < 8; ++j) {
            float old = Mv[j];
            p1 = fmaf(wv[j], old, p1);
            Mv[j] = fmaf(wv[j], fmaf(-old, e_c, a_c), old);
        }
        float part = p0 + p1;
        part += swz_xor4(part);
        part += quad_swap2(part);
        part += quad_swap1(part);
        if (p == 0) rp[(size_t)(t0 + u) * DIM] = part;
    }
}

__global__ __launch_bounds__(256) void kC(const float* __restrict__ Mv0,
                                          const float* __restrict__ w_in,
                                          const float2* __restrict__ ea_in,
                                          float* __restrict__ read_buf) {
    __shared__ __align__(16) float  wlds[2][32][64];    // 16 KB
    __shared__ __align__(16) float2 ealds[2][32][32];   // 16 KB
    const int tid = threadIdx.x;
    const int lane = tid & 63;
    const int wvid = tid >> 6;
    const int p = tid & 7;
    const int dl = tid >> 3;
    const int ds = blockIdx.x, b = blockIdx.y;
    const int d = ds * 32 + dl;
    const int m0 = p * 8;

    const char* wsrc  = (const char*)(w_in + (size_t)b * LL * MM);
    const char* easrc = (const char*)(ea_in + (size_t)b * LL * DIM + ds * 32);
    float* rp = read_buf + (size_t)b * LL * DIM + d;

    // DMA one 32-step tile (w: 8KB contiguous; ea: 32 rows x 256B, row stride 1KB)
    auto dma = [&](int c, int bufi) {
        const char* wt = wsrc + (size_t)c * 8192;
        char* wl = (char*)&wlds[bufi][0][0];
        char* el = (char*)&ealds[bufi][0][0];
        #pragma unroll
        for (int i = 0; i < 2; ++i) {
            const int off = wvid * 2048 + i * 1024 + lane * 16;
            ld16(wt + off, wl + off);
            const int tl = off >> 8, wi = off & 255;
            ld16(easrc + (size_t)(c * 32 + tl) * (DIM * 8) + wi, el + off);
        }
    };

    dma(0, 0);

    float Mv[8];
    #pragma unroll
    for (int j = 0; j < 8; ++j)
        Mv[j] = Mv0[(m0 + j) * DIM + d];

    int buf = 0;
    for (int c = 0; c < LL / 32; ++c) {
        __builtin_amdgcn_s_waitcnt(0x0F70);   // vmcnt(0): tile-c DMA landed
        __syncthreads();
        if (c + 1 < LL / 32) dma(c + 1, buf ^ 1);
        scan32(&wlds[buf][0][0], &ealds[buf][0][0], m0, dl, p, c * 32, Mv, rp);
        buf ^= 1;
    }
}

// ---------------------------------------------------------------------------
// Kernel D (MFMA): f = tanh([read,k]@Wf+bf); p = sigmoid(f@Wp+bp). 64 rows/blk.
// ---------------------------------------------------------------------------
__global__ __launch_bounds__(256) void kD(const int* __restrict__ q,
                                          const float* __restrict__ Ek,
                                          const u16* __restrict__ wfT_hi, const u16* __restrict__ wfT_lo,
                                          const float* __restrict__ bfv,
                                          const float* __restrict__ Wp, const float* __restrict__ bp,
                                          const float* __restrict__ read_buf,
                                          float* __restrict__ out) {
    __shared__ __align__(16) u16 xhi[4][16][264];
    __shared__ __align__(16) u16 xlo[4][16][264];
    __shared__ float sred[64][4];
    const int tid = threadIdx.x;
    const int base = blockIdx.x * 64;
    const int row_l = tid >> 2;
    const int rts = row_l >> 4, ms = row_l & 15;
    const int d0 = (tid & 3) * 32;
    const int row = base + row_l;

    {   // x[:, 0:128) = read_buf
        const float* src = read_buf + (size_t)row * DIM + d0;
        #pragma unroll
        for (int c8 = 0; c8 < 4; ++c8) {
            bfrag h, l;
            split8(src + c8 * 8, h, l);
            *reinterpret_cast<bfrag*>(&xhi[rts][ms][d0 + c8 * 8]) = h;
            *reinterpret_cast<bfrag*>(&xlo[rts][ms][d0 + c8 * 8]) = l;
        }
    }
    {   // x[:, 128:256) = Ek[q[row]]
        const float* src = Ek + (size_t)q[row] * DIM + d0;
        #pragma unroll
        for (int c8 = 0; c8 < 4; ++c8) {
            bfrag h, l;
            split8(src + c8 * 8, h, l);
            *reinterpret_cast<bfrag*>(&xhi[rts][ms][128 + d0 + c8 * 8]) = h;
            *reinterpret_cast<bfrag*>(&xlo[rts][ms][128 + d0 + c8 * 8]) = l;
        }
    }
    __syncthreads();

    const int lane = tid & 63;
    const int wv = tid >> 6;
    const int nloc = lane & 15;
    const int quad = lane >> 4;
    float* fbuf = reinterpret_cast<float*>(&xhi[0][0][0]);   // overlay after sync

    f32x4 acc[2][4];
    #pragma unroll
    for (int dt = 0; dt < 2; ++dt)
        #pragma unroll
        for (int t = 0; t < 4; ++t) acc[dt][t] = 0.f;

    #pragma unroll
    for (int dt = 0; dt < 2; ++dt) {
        const int n = (wv * 2 + dt) * 16 + nloc;
        bfrag Bh[8], Bl[8];
        #pragma unroll
        for (int kc = 0; kc < 8; ++kc) {
            const int ko = kc * 32 + quad * 8;
            Bh[kc] = *reinterpret_cast<const bfrag*>(wfT_hi + n * 256 + ko);
            Bl[kc] = *reinterpret_cast<const bfrag*>(wfT_lo + n * 256 + ko);
        }
        #pragma unroll
        for (int rt = 0; rt < 4; ++rt) {
            #pragma unroll
            for (int kc = 0; kc < 8; ++kc) {
                const int ko = kc * 32 + quad * 8;
                bfrag Ah = *reinterpret_cast<const bfrag*>(&xhi[rt][nloc][ko]);
                bfrag Al = *reinterpret_cast<const bfrag*>(&xlo[rt][nloc][ko]);
                acc[dt][rt] = __builtin_amdgcn_mfma_f32_16x16x32_bf16(Ah, Bh[kc], acc[dt][rt], 0, 0, 0);
                acc[dt][rt] = __builtin_amdgcn_mfma_f32_16x16x32_bf16(Ah, Bl[kc], acc[dt][rt], 0, 0, 0);
                acc[dt][rt] = __builtin_amdgcn_mfma_f32_16x16x32_bf16(Al, Bh[kc], acc[dt][rt], 0, 0, 0);
            }
        }
    }
    __syncthreads();   // LDS x reads done before fbuf overlay

    #pragma unroll
    for (int dt = 0; dt < 2; ++dt) {
        const int n = (wv * 2 + dt) * 16 + nloc;
        const float bfn = bfv[n], wpn = Wp[n];
        #pragma unroll
        for (int rt = 0; rt < 4; ++rt)
            #pragma unroll
            for (int rg = 0; rg < 4; ++rg)
                fbuf[(rt * 16 + quad * 4 + rg) * 132 + n] = tanhf_fast(acc[dt][rt][rg] + bfn) * wpn;
    }
    __syncthreads();

    {
        float s = 0.f;
        const int c = tid & 3;
        #pragma unroll
        for (int k = 0; k < 32; ++k) s += fbuf[row_l * 132 + c * 32 + k];
        sred[row_l][c] = s;
    }
    __syncthreads();
    if (tid < 64)
        out[base + tid] = sigmoidf_fast(sred[tid][0] + sred[tid][1] + sred[tid][2] + sred[tid][3] + bp[0]);
}

// ---------------------------------------------------------------------------
extern "C" void kernel_launch(void* const* d_in, const int* in_sizes, int n_in,
                              void* d_out, int out_size, void* d_ws, size_t ws_size,
                              hipStream_t stream) {
    const int*   q   = (const int*)d_in[0];
    const int*   r   = (const int*)d_in[1];
    const float* Ek  = (const float*)d_in[2];
    const float* Ev  = (const float*)d_in[3];
    const float* Mk  = (const float*)d_in[4];
    const float* Mv0 = (const float*)d_in[5];
    const float* We  = (const float*)d_in[6];
    const float* be  = (const float*)d_in[7];
    const float* Wa  = (const float*)d_in[8];
    const float* ba  = (const float*)d_in[9];
    const float* Wf  = (const float*)d_in[10];
    const float* bfv = (const float*)d_in[11];
    const float* Wp  = (const float*)d_in[12];
    const float* bp  = (const float*)d_in[13];
    float* out = (float*)d_out;

    float*  ws     = (float*)d_ws;
    float*  w_buf  = ws;                                      // 8 MB
    float2* ea_buf = (float2*)(w_buf + (size_t)NROWS * MM);   // 32 MB
    float*  rd_buf = (float*)(ea_buf + (size_t)NROWS * DIM);  // 16 MB

    // prepped bf16 weights at the END of ws (288 KB)
    size_t prep_off = (ws_size - (size_t)294912) & ~(size_t)255;
    u16* weT_hi = (u16*)((char*)d_ws + prep_off);
    u16* weT_lo = weT_hi + 16384;
    u16* waT_hi = weT_lo + 16384;
    u16* waT_lo = waT_hi + 16384;
    u16* wfT_hi = waT_lo + 16384;
    u16* wfT_lo = wfT_hi + 32768;
    u16* mkT_hi = wfT_lo + 32768;
    u16* mkT_lo = mkT_hi + 8192;

    kP<<<dim3(128), 256, 0, stream>>>(We, Wa, Wf, Mk, weT_hi, weT_lo, waT_hi, waT_lo,
                                      wfT_hi, wfT_lo, mkT_hi, mkT_lo);
    kA<<<dim3(NROWS / 64), 256, 0, stream>>>(q, Ek, mkT_hi, mkT_lo, w_buf);
    kB<<<dim3(NROWS / 64), 256, 0, stream>>>(q, r, Ev, weT_hi, weT_lo, waT_hi, waT_lo,
                                             be, ba, ea_buf);
    kC<<<dim3(4, BB), 256, 0, stream>>>(Mv0, w_buf, ea_buf, rd_buf);
    kD<<<dim3(NROWS / 64), 256, 0, stream>>>(q, Ek, wfT_hi, wfT_lo, bfv, Wp, bp, rd_buf, out);
}

// Round 12
// 192.515 us; speedup vs baseline: 1.2546x; 1.0404x over previous
//
#include <hip/hip_runtime.h>
#include <hip/hip_bf16.h>

#define NUM_C 1000
#define DIM   128
#define MM    64
#define BB    64
#define LL    512
#define NROWS (BB * LL)   // 32768

typedef unsigned short u16;
typedef unsigned int   u32;
typedef short bfrag __attribute__((ext_vector_type(8)));   // 8 bf16 (4 VGPRs)
typedef float f32x4 __attribute__((ext_vector_type(4)));   // MFMA acc

__device__ __forceinline__ float sigmoidf_fast(float x) { return 1.f / (1.f + __expf(-x)); }
__device__ __forceinline__ float tanhf_fast(float x) { return 1.f - 2.f / (__expf(2.f * x) + 1.f); }

__device__ __forceinline__ u16 f2bf(float x) {            // RNE f32->bf16 bits
    u32 u = __float_as_uint(x);
    return (u16)((u + 0x7FFFu + ((u >> 16) & 1u)) >> 16);
}
__device__ __forceinline__ float bf2f(u16 h) { return __uint_as_float(((u32)h) << 16); }

// DPP quad_perm swaps (VALU-only, verified rounds 5-11)
__device__ __forceinline__ float quad_swap1(float x) {
    return __int_as_float(__builtin_amdgcn_mov_dpp(__float_as_int(x), 0xB1, 0xF, 0xF, true));
}
__device__ __forceinline__ float quad_swap2(float x) {
    return __int_as_float(__builtin_amdgcn_mov_dpp(__float_as_int(x), 0x4E, 0xF, 0xF, true));
}

// async global->LDS DMA, 16B per lane, LDS dest = wave-uniform base + lane*16
__device__ __forceinline__ void ld16(const void* g, void* l) {
    __builtin_amdgcn_global_load_lds(
        (const __attribute__((address_space(1))) unsigned int*)g,
        (__attribute__((address_space(3))) unsigned int*)l, 16, 0, 0);
}

// ---------------------------------------------------------------------------
// Prep: bf16 hi/lo weights. weT/waT [n][k], wfT [n][k] (transposed), mkT = Mk.
// ---------------------------------------------------------------------------
__global__ __launch_bounds__(256) void kP(const float* __restrict__ We,
                                          const float* __restrict__ Wa,
                                          const float* __restrict__ Wf,
                                          const float* __restrict__ Mk,
                                          u16* weT_hi, u16* weT_lo,
                                          u16* waT_hi, u16* waT_lo,
                                          u16* wfT_hi, u16* wfT_lo,
                                          u16* mkT_hi, u16* mkT_lo) {
    int idx = blockIdx.x * 256 + threadIdx.x;   // 0..32767
    if (idx < 128 * 128) {
        int n = idx >> 7, k = idx & 127;
        float we = We[k * DIM + n];
        u16 h = f2bf(we);
        weT_hi[idx] = h; weT_lo[idx] = f2bf(we - bf2f(h));
        float wa = Wa[k * DIM + n];
        u16 h2 = f2bf(wa);
        waT_hi[idx] = h2; waT_lo[idx] = f2bf(wa - bf2f(h2));
    }
    if (idx < 64 * 128) {
        float mk = Mk[idx];
        u16 h = f2bf(mk);
        mkT_hi[idx] = h; mkT_lo[idx] = f2bf(mk - bf2f(h));
    }
    {
        int n = idx >> 8, k = idx & 255;
        float wf = Wf[k * DIM + n];
        u16 h = f2bf(wf);
        wfT_hi[idx] = h; wfT_lo[idx] = f2bf(wf - bf2f(h));
    }
}

// helper: split float8 chunk to bf16 hi/lo frags
__device__ __forceinline__ void split8(const float* src, bfrag& h, bfrag& l) {
    float4 f0 = *reinterpret_cast<const float4*>(src);
    float4 f1 = *reinterpret_cast<const float4*>(src + 4);
    float xs[8] = {f0.x, f0.y, f0.z, f0.w, f1.x, f1.y, f1.z, f1.w};
    #pragma unroll
    for (int j = 0; j < 8; ++j) {
        u16 hb = f2bf(xs[j]);
        h[j] = (short)hb;
        l[j] = (short)f2bf(xs[j] - bf2f(hb));
    }
}

// ---------------------------------------------------------------------------
// Kernel A (MFMA): w[row][m] = softmax_m(Ek[q[row]] . Mk[m]); 64 rows/block.
// ---------------------------------------------------------------------------
__global__ __launch_bounds__(256) void kA(const int* __restrict__ q,
                                          const float* __restrict__ Ek,
                                          const u16* __restrict__ mkT_hi,
                                          const u16* __restrict__ mkT_lo,
                                          float* __restrict__ w_out) {
    __shared__ __align__(16) u16 khi[4][16][136];
    __shared__ __align__(16) u16 klo[4][16][136];
    __shared__ float slab[4][64];
    const int tid = threadIdx.x;
    const int base = blockIdx.x * 64;

    {   // stage
        const int row_l = tid >> 2;
        const int rts = row_l >> 4, ms = row_l & 15;
        const int d0 = (tid & 3) * 32;
        const float* src = Ek + (size_t)q[base + row_l] * DIM + d0;
        #pragma unroll
        for (int c8 = 0; c8 < 4; ++c8) {
            bfrag h, l;
            split8(src + c8 * 8, h, l);
            *reinterpret_cast<bfrag*>(&khi[rts][ms][d0 + c8 * 8]) = h;
            *reinterpret_cast<bfrag*>(&klo[rts][ms][d0 + c8 * 8]) = l;
        }
    }
    __syncthreads();

    const int lane = tid & 63;
    const int wv = tid >> 6;
    const int nloc = lane & 15;
    const int quad = lane >> 4;
    const int n = wv * 16 + nloc;      // m index

    bfrag Bh[4], Bl[4];
    #pragma unroll
    for (int kc = 0; kc < 4; ++kc) {
        const int ko = kc * 32 + quad * 8;
        Bh[kc] = *reinterpret_cast<const bfrag*>(mkT_hi + n * DIM + ko);
        Bl[kc] = *reinterpret_cast<const bfrag*>(mkT_lo + n * DIM + ko);
    }

    f32x4 acc[4];
    #pragma unroll
    for (int t = 0; t < 4; ++t) acc[t] = 0.f;

    #pragma unroll
    for (int rt = 0; rt < 4; ++rt) {
        #pragma unroll
        for (int kc = 0; kc < 4; ++kc) {
            const int ko = kc * 32 + quad * 8;
            bfrag Ah = *reinterpret_cast<const bfrag*>(&khi[rt][nloc][ko]);
            bfrag Al = *reinterpret_cast<const bfrag*>(&klo[rt][nloc][ko]);
            acc[rt] = __builtin_amdgcn_mfma_f32_16x16x32_bf16(Ah, Bh[kc], acc[rt], 0, 0, 0);
            acc[rt] = __builtin_amdgcn_mfma_f32_16x16x32_bf16(Ah, Bl[kc], acc[rt], 0, 0, 0);
            acc[rt] = __builtin_amdgcn_mfma_f32_16x16x32_bf16(Al, Bh[kc], acc[rt], 0, 0, 0);
        }
    }

    float ex[4][4];
    #pragma unroll
    for (int rt = 0; rt < 4; ++rt) {
        #pragma unroll
        for (int rg = 0; rg < 4; ++rg) {
            float e = __expf(acc[rt][rg]);
            ex[rt][rg] = e;
            float s = e;
            s += __shfl_xor(s, 1);
            s += __shfl_xor(s, 2);
            s += __shfl_xor(s, 4);
            s += __shfl_xor(s, 8);
            if (nloc == 0) slab[wv][rt * 16 + quad * 4 + rg] = s;
        }
    }
    __syncthreads();

    #pragma unroll
    for (int rt = 0; rt < 4; ++rt) {
        #pragma unroll
        for (int rg = 0; rg < 4; ++rg) {
            const int row = rt * 16 + quad * 4 + rg;
            float tot = slab[0][row] + slab[1][row] + slab[2][row] + slab[3][row];
            w_out[(size_t)(base + row) * MM + n] = ex[rt][rg] / tot;
        }
    }
}

// ---------------------------------------------------------------------------
// Kernel B (MFMA): e/a, written interleaved as float2 ea_buf[row*DIM+d].
// ---------------------------------------------------------------------------
__global__ __launch_bounds__(256) void kB(const int* __restrict__ q,
                                          const int* __restrict__ r,
                                          const float* __restrict__ Ev,
                                          const u16* __restrict__ weT_hi, const u16* __restrict__ weT_lo,
                                          const u16* __restrict__ waT_hi, const u16* __restrict__ waT_lo,
                                          const float* __restrict__ be, const float* __restrict__ ba,
                                          float2* __restrict__ ea_out) {
    __shared__ __align__(16) u16 vhi[4][16][136];
    __shared__ __align__(16) u16 vlo[4][16][136];
    const int tid = threadIdx.x;
    const int base = blockIdx.x * 64;

    {   // stage
        const int row_l = tid >> 2;
        const int rts = row_l >> 4, ms = row_l & 15;
        const int d0 = (tid & 3) * 32;
        const int row = base + row_l;
        const int x = q[row] + NUM_C * r[row];
        const float* src = Ev + (size_t)x * DIM + d0;
        #pragma unroll
        for (int c8 = 0; c8 < 4; ++c8) {
            bfrag h, l;
            split8(src + c8 * 8, h, l);
            *reinterpret_cast<bfrag*>(&vhi[rts][ms][d0 + c8 * 8]) = h;
            *reinterpret_cast<bfrag*>(&vlo[rts][ms][d0 + c8 * 8]) = l;
        }
    }
    __syncthreads();

    const int lane = tid & 63;
    const int wv = tid >> 6;
    const int nloc = lane & 15;
    const int quad = lane >> 4;

    #pragma unroll
    for (int dt = 0; dt < 2; ++dt) {
        const int n = (wv * 2 + dt) * 16 + nloc;
        bfrag Beh[4], Bel[4], Bah[4], Bal[4];
        #pragma unroll
        for (int kc = 0; kc < 4; ++kc) {
            const int ko = kc * 32 + quad * 8;
            Beh[kc] = *reinterpret_cast<const bfrag*>(weT_hi + n * DIM + ko);
            Bel[kc] = *reinterpret_cast<const bfrag*>(weT_lo + n * DIM + ko);
            Bah[kc] = *reinterpret_cast<const bfrag*>(waT_hi + n * DIM + ko);
            Bal[kc] = *reinterpret_cast<const bfrag*>(waT_lo + n * DIM + ko);
        }
        f32x4 acc_e[4], acc_a[4];
        #pragma unroll
        for (int t = 0; t < 4; ++t) { acc_e[t] = 0.f; acc_a[t] = 0.f; }

        #pragma unroll
        for (int rt = 0; rt < 4; ++rt) {
            #pragma unroll
            for (int kc = 0; kc < 4; ++kc) {
                const int ko = kc * 32 + quad * 8;
                bfrag Ah = *reinterpret_cast<const bfrag*>(&vhi[rt][nloc][ko]);
                bfrag Al = *reinterpret_cast<const bfrag*>(&vlo[rt][nloc][ko]);
                acc_e[rt] = __builtin_amdgcn_mfma_f32_16x16x32_bf16(Ah, Beh[kc], acc_e[rt], 0, 0, 0);
                acc_a[rt] = __builtin_amdgcn_mfma_f32_16x16x32_bf16(Ah, Bah[kc], acc_a[rt], 0, 0, 0);
                acc_e[rt] = __builtin_amdgcn_mfma_f32_16x16x32_bf16(Ah, Bel[kc], acc_e[rt], 0, 0, 0);
                acc_a[rt] = __builtin_amdgcn_mfma_f32_16x16x32_bf16(Ah, Bal[kc], acc_a[rt], 0, 0, 0);
                acc_e[rt] = __builtin_amdgcn_mfma_f32_16x16x32_bf16(Al, Beh[kc], acc_e[rt], 0, 0, 0);
                acc_a[rt] = __builtin_amdgcn_mfma_f32_16x16x32_bf16(Al, Bah[kc], acc_a[rt], 0, 0, 0);
            }
        }
        const float bev = be[n], bav = ba[n];
        #pragma unroll
        for (int rt = 0; rt < 4; ++rt) {
            #pragma unroll
            for (int rg = 0; rg < 4; ++rg) {
                const int row = base + rt * 16 + quad * 4 + rg;
                float2 ea;
                ea.x = sigmoidf_fast(acc_e[rt][rg] + bev);
                ea.y = tanhf_fast(acc_a[rt][rg] + bav);
                ea_out[(size_t)row * DIM + n] = ea;
            }
        }
    }
}

// ---------------------------------------------------------------------------
// Kernel C: scan, async-DMA LDS tiles, VALU-only reduce, half-sum stores.
// Grid (ds=4, b=64), 256 thr. Thread: p = tid&7 owns 8 m; dl = tid>>3.
// Per step: 3 ds_reads + 24 FMA + xor1/xor2 DPP reduce; lanes p=0/p=4 store
// the two quad half-sums to rd2[b][t][2d+half]; kD adds them. No ds_swizzle,
// no full vmcnt drain (vmcnt(32) leaves stores in flight; 4 DMAs are oldest).
// ---------------------------------------------------------------------------
__device__ __forceinline__ void scan32(const float* wb, const float2* eab,
                                       int m0, int dl, int p, int t0,
                                       float (&Mv)[8], float* rp2) {
    #pragma unroll
    for (int u = 0; u < 32; ++u) {
        float4 w0 = *reinterpret_cast<const float4*>(wb + u * 64 + m0);
        float4 w1 = *reinterpret_cast<const float4*>(wb + u * 64 + m0 + 4);
        float2 ea = eab[u * 32 + dl];
        float wv[8] = {w0.x, w0.y, w0.z, w0.w, w1.x, w1.y, w1.z, w1.w};
        float e_c = ea.x, a_c = ea.y;
        float p0 = 0.f, p1 = 0.f;
        #pragma unroll
        for (int j = 0; j < 4; ++j) {
            float old = Mv[j];
            p0 = fmaf(wv[j], old, p0);                       // read BEFORE update
            Mv[j] = fmaf(wv[j], fmaf(-old, e_c, a_c), old);
        }
        #pragma unroll
        for (int j = 4; j < 8; ++j) {
            float old = Mv[j];
            p1 = fmaf(wv[j], old, p1);
            Mv[j] = fmaf(wv[j], fmaf(-old, e_c, a_c), old);
        }
        float part = p0 + p1;
        part += quad_swap1(part);
        part += quad_swap2(part);     // lanes in quad all hold quad-sum
        if ((p & 3) == 0)             // p==0 -> half 0, p==4 -> half 1
            rp2[(size_t)(t0 + u) * (2 * DIM)] = part;
    }
}

__global__ __launch_bounds__(256) void kC(const float* __restrict__ Mv0,
                                          const float* __restrict__ w_in,
                                          const float2* __restrict__ ea_in,
                                          float* __restrict__ rd2) {
    __shared__ __align__(16) float  wlds[2][32][64];    // 16 KB
    __shared__ __align__(16) float2 ealds[2][32][32];   // 16 KB
    const int tid = threadIdx.x;
    const int lane = tid & 63;
    const int wvid = tid >> 6;
    const int p = tid & 7;
    const int dl = tid >> 3;
    const int ds = blockIdx.x, b = blockIdx.y;
    const int d = ds * 32 + dl;
    const int m0 = p * 8;

    const char* wsrc  = (const char*)(w_in + (size_t)b * LL * MM);
    const char* easrc = (const char*)(ea_in + (size_t)b * LL * DIM + ds * 32);
    float* rp2 = rd2 + (size_t)b * LL * (2 * DIM) + (size_t)d * 2 + (p >> 2);

    auto dma = [&](int c, int bufi) {
        const char* wt = wsrc + (size_t)c * 8192;
        char* wl = (char*)&wlds[bufi][0][0];
        char* el = (char*)&ealds[bufi][0][0];
        #pragma unroll
        for (int i = 0; i < 2; ++i) {
            const int off = wvid * 2048 + i * 1024 + lane * 16;
            ld16(wt + off, wl + off);
            const int tl = off >> 8, wi = off & 255;
            ld16(easrc + (size_t)(c * 32 + tl) * (DIM * 8) + wi, el + off);
        }
    };

    dma(0, 0);

    float Mv[8];
    #pragma unroll
    for (int j = 0; j < 8; ++j)
        Mv[j] = Mv0[(m0 + j) * DIM + d];

    __builtin_amdgcn_s_waitcnt(0x0F70);   // vmcnt(0): tile-0 DMA + Mv loads done
    __syncthreads();

    int buf = 0;
    for (int c = 0; c < LL / 32; ++c) {
        if (c + 1 < LL / 32) dma(c + 1, buf ^ 1);
        scan32(&wlds[buf][0][0], &ealds[buf][0][0], m0, dl, p, c * 32, Mv, rp2);
        if (c + 1 < LL / 32) {
            // 36 outstanding vmem ops: [4 DMA (oldest)][32 stores]. Waiting to
            // <=32 retires the DMAs without draining the stores (AITER-style).
            __builtin_amdgcn_s_waitcnt(0x8F70);   // vmcnt(32)
            __syncthreads();
            buf ^= 1;
        }
    }
}

// ---------------------------------------------------------------------------
// Kernel D (MFMA): read[d] = rd2[2d]+rd2[2d+1]; f = tanh([read,k]@Wf+bf);
// p = sigmoid(f@Wp+bp). 64 rows/block.
// ---------------------------------------------------------------------------
__global__ __launch_bounds__(256) void kD(const int* __restrict__ q,
                                          const float* __restrict__ Ek,
                                          const u16* __restrict__ wfT_hi, const u16* __restrict__ wfT_lo,
                                          const float* __restrict__ bfv,
                                          const float* __restrict__ Wp, const float* __restrict__ bp,
                                          const float* __restrict__ rd2,
                                          float* __restrict__ out) {
    __shared__ __align__(16) u16 xhi[4][16][264];
    __shared__ __align__(16) u16 xlo[4][16][264];
    __shared__ float sred[64][4];
    const int tid = threadIdx.x;
    const int base = blockIdx.x * 64;
    const int row_l = tid >> 2;
    const int rts = row_l >> 4, ms = row_l & 15;
    const int d0 = (tid & 3) * 32;
    const int row = base + row_l;

    {   // x[:, 0:128) = read (sum of the two stored halves)
        const float2* src2 = reinterpret_cast<const float2*>(rd2 + (size_t)row * (2 * DIM)) + d0;
        #pragma unroll
        for (int c8 = 0; c8 < 4; ++c8) {
            float xs[8];
            #pragma unroll
            for (int j = 0; j < 8; ++j) {
                float2 v = src2[c8 * 8 + j];
                xs[j] = v.x + v.y;
            }
            bfrag h, l;
            #pragma unroll
            for (int j = 0; j < 8; ++j) {
                u16 hb = f2bf(xs[j]);
                h[j] = (short)hb;
                l[j] = (short)f2bf(xs[j] - bf2f(hb));
            }
            *reinterpret_cast<bfrag*>(&xhi[rts][ms][d0 + c8 * 8]) = h;
            *reinterpret_cast<bfrag*>(&xlo[rts][ms][d0 + c8 * 8]) = l;
        }
    }
    {   // x[:, 128:256) = Ek[q[row]]
        const float* src = Ek + (size_t)q[row] * DIM + d0;
        #pragma unroll
        for (int c8 = 0; c8 < 4; ++c8) {
            bfrag h, l;
            split8(src + c8 * 8, h, l);
            *reinterpret_cast<bfrag*>(&xhi[rts][ms][128 + d0 + c8 * 8]) = h;
            *reinterpret_cast<bfrag*>(&xlo[rts][ms][128 + d0 + c8 * 8]) = l;
        }
    }
    __syncthreads();

    const int lane = tid & 63;
    const int wv = tid >> 6;
    const int nloc = lane & 15;
    const int quad = lane >> 4;
    float* fbuf = reinterpret_cast<float*>(&xhi[0][0][0]);   // overlay after sync

    f32x4 acc[2][4];
    #pragma unroll
    for (int dt = 0; dt < 2; ++dt)
        #pragma unroll
        for (int t = 0; t < 4; ++t) acc[dt][t] = 0.f;

    #pragma unroll
    for (int dt = 0; dt < 2; ++dt) {
        const int n = (wv * 2 + dt) * 16 + nloc;
        bfrag Bh[8], Bl[8];
        #pragma unroll
        for (int kc = 0; kc < 8; ++kc) {
            const int ko = kc * 32 + quad * 8;
            Bh[kc] = *reinterpret_cast<const bfrag*>(wfT_hi + n * 256 + ko);
            Bl[kc] = *reinterpret_cast<const bfrag*>(wfT_lo + n * 256 + ko);
        }
        #pragma unroll
        for (int rt = 0; rt < 4; ++rt) {
            #pragma unroll
            for (int kc = 0; kc < 8; ++kc) {
                const int ko = kc * 32 + quad * 8;
                bfrag Ah = *reinterpret_cast<const bfrag*>(&xhi[rt][nloc][ko]);
                bfrag Al = *reinterpret_cast<const bfrag*>(&xlo[rt][nloc][ko]);
                acc[dt][rt] = __builtin_amdgcn_mfma_f32_16x16x32_bf16(Ah, Bh[kc], acc[dt][rt], 0, 0, 0);
                acc[dt][rt] = __builtin_amdgcn_mfma_f32_16x16x32_bf16(Ah, Bl[kc], acc[dt][rt], 0, 0, 0);
                acc[dt][rt] = __builtin_amdgcn_mfma_f32_16x16x32_bf16(Al, Bh[kc], acc[dt][rt], 0, 0, 0);
            }
        }
    }
    __syncthreads();   // LDS x reads done before fbuf overlay

    #pragma unroll
    for (int dt = 0; dt < 2; ++dt) {
        const int n = (wv * 2 + dt) * 16 + nloc;
        const float bfn = bfv[n], wpn = Wp[n];
        #pragma unroll
        for (int rt = 0; rt < 4; ++rt)
            #pragma unroll
            for (int rg = 0; rg < 4; ++rg)
                fbuf[(rt * 16 + quad * 4 + rg) * 132 + n] = tanhf_fast(acc[dt][rt][rg] + bfn) * wpn;
    }
    __syncthreads();

    {
        float s = 0.f;
        const int c = tid & 3;
        #pragma unroll
        for (int k = 0; k < 32; ++k) s += fbuf[row_l * 132 + c * 32 + k];
        sred[row_l][c] = s;
    }
    __syncthreads();
    if (tid < 64)
        out[base + tid] = sigmoidf_fast(sred[tid][0] + sred[tid][1] + sred[tid][2] + sred[tid][3] + bp[0]);
}

// ---------------------------------------------------------------------------
extern "C" void kernel_launch(void* const* d_in, const int* in_sizes, int n_in,
                              void* d_out, int out_size, void* d_ws, size_t ws_size,
                              hipStream_t stream) {
    const int*   q   = (const int*)d_in[0];
    const int*   r   = (const int*)d_in[1];
    const float* Ek  = (const float*)d_in[2];
    const float* Ev  = (const float*)d_in[3];
    const float* Mk  = (const float*)d_in[4];
    const float* Mv0 = (const float*)d_in[5];
    const float* We  = (const float*)d_in[6];
    const float* be  = (const float*)d_in[7];
    const float* Wa  = (const float*)d_in[8];
    const float* ba  = (const float*)d_in[9];
    const float* Wf  = (const float*)d_in[10];
    const float* bfv = (const float*)d_in[11];
    const float* Wp  = (const float*)d_in[12];
    const float* bp  = (const float*)d_in[13];
    float* out = (float*)d_out;

    float*  ws     = (float*)d_ws;
    float*  w_buf  = ws;                                      // 8 MB
    float2* ea_buf = (float2*)(w_buf + (size_t)NROWS * MM);   // 32 MB
    float*  rd2    = (float*)(ea_buf + (size_t)NROWS * DIM);  // 32 MB (2 halves)

    // prepped bf16 weights at the END of ws (288 KB)
    size_t prep_off = (ws_size - (size_t)294912) & ~(size_t)255;
    u16* weT_hi = (u16*)((char*)d_ws + prep_off);
    u16* weT_lo = weT_hi + 16384;
    u16* waT_hi = weT_lo + 16384;
    u16* waT_lo = waT_hi + 16384;
    u16* wfT_hi = waT_lo + 16384;
    u16* wfT_lo = wfT_hi + 32768;
    u16* mkT_hi = wfT_lo + 32768;
    u16* mkT_lo = mkT_hi + 8192;

    kP<<<dim3(128), 256, 0, stream>>>(We, Wa, Wf, Mk, weT_hi, weT_lo, waT_hi, waT_lo,
                                      wfT_hi, wfT_lo, mkT_hi, mkT_lo);
    kA<<<dim3(NROWS / 64), 256, 0, stream>>>(q, Ek, mkT_hi, mkT_lo, w_buf);
    kB<<<dim3(NROWS / 64), 256, 0, stream>>>(q, r, Ev, weT_hi, weT_lo, waT_hi, waT_lo,
                                             be, ba, ea_buf);
    kC<<<dim3(4, BB), 256, 0, stream>>>(Mv0, w_buf, ea_buf, rd2);
    kD<<<dim3(NROWS / 64), 256, 0, stream>>>(q, Ek, wfT_hi, wfT_lo, bfv, Wp, bp, rd2, out);
}

// Round 13
// 182.670 us; speedup vs baseline: 1.3222x; 1.0539x over previous
//
#include <hip/hip_runtime.h>
#include <hip/hip_bf16.h>

#define NUM_C 1000
#define DIM   128
#define MM    64
#define BB    64
#define LL    512
#define NROWS (BB * LL)   // 32768

typedef unsigned short u16;
typedef unsigned int   u32;
typedef short bfrag __attribute__((ext_vector_type(8)));   // 8 bf16 (4 VGPRs)
typedef float f32x4 __attribute__((ext_vector_type(4)));   // MFMA acc

__device__ __forceinline__ float sigmoidf_fast(float x) { return 1.f / (1.f + __expf(-x)); }
__device__ __forceinline__ float tanhf_fast(float x) { return 1.f - 2.f / (__expf(2.f * x) + 1.f); }

__device__ __forceinline__ u16 f2bf(float x) {            // RNE f32->bf16 bits
    u32 u = __float_as_uint(x);
    return (u16)((u + 0x7FFFu + ((u >> 16) & 1u)) >> 16);
}
__device__ __forceinline__ float bf2f(u16 h) { return __uint_as_float(((u32)h) << 16); }

// DPP quad_perm swaps (VALU-only, verified rounds 5-12)
__device__ __forceinline__ float quad_swap1(float x) {
    return __int_as_float(__builtin_amdgcn_mov_dpp(__float_as_int(x), 0xB1, 0xF, 0xF, true));
}
__device__ __forceinline__ float quad_swap2(float x) {
    return __int_as_float(__builtin_amdgcn_mov_dpp(__float_as_int(x), 0x4E, 0xF, 0xF, true));
}

// async global->LDS DMA, 16B per lane, LDS dest = wave-uniform base + lane*16
__device__ __forceinline__ void ld16(const void* g, void* l) {
    __builtin_amdgcn_global_load_lds(
        (const __attribute__((address_space(1))) unsigned int*)g,
        (__attribute__((address_space(3))) unsigned int*)l, 16, 0, 0);
}

// ---------------------------------------------------------------------------
// Prep: bf16 hi/lo weights. weT/waT [n][k], wfT [n][k] (transposed), mkT = Mk.
// ---------------------------------------------------------------------------
__global__ __launch_bounds__(256) void kP(const float* __restrict__ We,
                                          const float* __restrict__ Wa,
                                          const float* __restrict__ Wf,
                                          const float* __restrict__ Mk,
                                          u16* weT_hi, u16* weT_lo,
                                          u16* waT_hi, u16* waT_lo,
                                          u16* wfT_hi, u16* wfT_lo,
                                          u16* mkT_hi, u16* mkT_lo) {
    int idx = blockIdx.x * 256 + threadIdx.x;   // 0..32767
    if (idx < 128 * 128) {
        int n = idx >> 7, k = idx & 127;
        float we = We[k * DIM + n];
        u16 h = f2bf(we);
        weT_hi[idx] = h; weT_lo[idx] = f2bf(we - bf2f(h));
        float wa = Wa[k * DIM + n];
        u16 h2 = f2bf(wa);
        waT_hi[idx] = h2; waT_lo[idx] = f2bf(wa - bf2f(h2));
    }
    if (idx < 64 * 128) {
        float mk = Mk[idx];
        u16 h = f2bf(mk);
        mkT_hi[idx] = h; mkT_lo[idx] = f2bf(mk - bf2f(h));
    }
    {
        int n = idx >> 8, k = idx & 255;
        float wf = Wf[k * DIM + n];
        u16 h = f2bf(wf);
        wfT_hi[idx] = h; wfT_lo[idx] = f2bf(wf - bf2f(h));
    }
}

// helper: split float8 chunk to bf16 hi/lo frags
__device__ __forceinline__ void split8(const float* src, bfrag& h, bfrag& l) {
    float4 f0 = *reinterpret_cast<const float4*>(src);
    float4 f1 = *reinterpret_cast<const float4*>(src + 4);
    float xs[8] = {f0.x, f0.y, f0.z, f0.w, f1.x, f1.y, f1.z, f1.w};
    #pragma unroll
    for (int j = 0; j < 8; ++j) {
        u16 hb = f2bf(xs[j]);
        h[j] = (short)hb;
        l[j] = (short)f2bf(xs[j] - bf2f(hb));
    }
}

// ---------------------------------------------------------------------------
// Fused kAB (MFMA). Blocks [0,512): kA role -> w = softmax(Ek[q].Mk^T).
// Blocks [512,1024): kB role -> e/a = sig/tanh(Ev[x]@We|Wa), float2 out.
// Both: 64 rows/block, 256 thr, shared 18 KB LDS staging.
// ---------------------------------------------------------------------------
__global__ __launch_bounds__(256) void kAB(const int* __restrict__ q,
                                           const int* __restrict__ r,
                                           const float* __restrict__ Ek,
                                           const float* __restrict__ Ev,
                                           const u16* __restrict__ mkT_hi, const u16* __restrict__ mkT_lo,
                                           const u16* __restrict__ weT_hi, const u16* __restrict__ weT_lo,
                                           const u16* __restrict__ waT_hi, const u16* __restrict__ waT_lo,
                                           const float* __restrict__ be, const float* __restrict__ ba,
                                           float* __restrict__ w_out,
                                           float2* __restrict__ ea_out) {
    __shared__ __align__(16) u16 shi[4][16][136];
    __shared__ __align__(16) u16 slo[4][16][136];
    __shared__ float slab[4][64];
    const int tid = threadIdx.x;
    const int lane = tid & 63;
    const int wv = tid >> 6;
    const int nloc = lane & 15;
    const int quad = lane >> 4;

    if (blockIdx.x < 512) {
        // ---------------- kA role ----------------
        const int base = blockIdx.x * 64;
        {   // stage k = Ek[q] as bf16 hi/lo
            const int row_l = tid >> 2;
            const int rts = row_l >> 4, ms = row_l & 15;
            const int d0 = (tid & 3) * 32;
            const float* src = Ek + (size_t)q[base + row_l] * DIM + d0;
            #pragma unroll
            for (int c8 = 0; c8 < 4; ++c8) {
                bfrag h, l;
                split8(src + c8 * 8, h, l);
                *reinterpret_cast<bfrag*>(&shi[rts][ms][d0 + c8 * 8]) = h;
                *reinterpret_cast<bfrag*>(&slo[rts][ms][d0 + c8 * 8]) = l;
            }
        }
        __syncthreads();

        const int n = wv * 16 + nloc;      // m index
        bfrag Bh[4], Bl[4];
        #pragma unroll
        for (int kc = 0; kc < 4; ++kc) {
            const int ko = kc * 32 + quad * 8;
            Bh[kc] = *reinterpret_cast<const bfrag*>(mkT_hi + n * DIM + ko);
            Bl[kc] = *reinterpret_cast<const bfrag*>(mkT_lo + n * DIM + ko);
        }

        f32x4 acc[4];
        #pragma unroll
        for (int t = 0; t < 4; ++t) acc[t] = 0.f;

        #pragma unroll
        for (int rt = 0; rt < 4; ++rt) {
            #pragma unroll
            for (int kc = 0; kc < 4; ++kc) {
                const int ko = kc * 32 + quad * 8;
                bfrag Ah = *reinterpret_cast<const bfrag*>(&shi[rt][nloc][ko]);
                bfrag Al = *reinterpret_cast<const bfrag*>(&slo[rt][nloc][ko]);
                acc[rt] = __builtin_amdgcn_mfma_f32_16x16x32_bf16(Ah, Bh[kc], acc[rt], 0, 0, 0);
                acc[rt] = __builtin_amdgcn_mfma_f32_16x16x32_bf16(Ah, Bl[kc], acc[rt], 0, 0, 0);
                acc[rt] = __builtin_amdgcn_mfma_f32_16x16x32_bf16(Al, Bh[kc], acc[rt], 0, 0, 0);
            }
        }

        float ex[4][4];
        #pragma unroll
        for (int rt = 0; rt < 4; ++rt) {
            #pragma unroll
            for (int rg = 0; rg < 4; ++rg) {
                float e = __expf(acc[rt][rg]);
                ex[rt][rg] = e;
                float s = e;
                s += __shfl_xor(s, 1);
                s += __shfl_xor(s, 2);
                s += __shfl_xor(s, 4);
                s += __shfl_xor(s, 8);
                if (nloc == 0) slab[wv][rt * 16 + quad * 4 + rg] = s;
            }
        }
        __syncthreads();

        #pragma unroll
        for (int rt = 0; rt < 4; ++rt) {
            #pragma unroll
            for (int rg = 0; rg < 4; ++rg) {
                const int row = rt * 16 + quad * 4 + rg;
                float tot = slab[0][row] + slab[1][row] + slab[2][row] + slab[3][row];
                w_out[(size_t)(base + row) * MM + n] = ex[rt][rg] / tot;
            }
        }
    } else {
        // ---------------- kB role ----------------
        const int base = (blockIdx.x - 512) * 64;
        {   // stage v = Ev[x] as bf16 hi/lo
            const int row_l = tid >> 2;
            const int rts = row_l >> 4, ms = row_l & 15;
            const int d0 = (tid & 3) * 32;
            const int row = base + row_l;
            const int x = q[row] + NUM_C * r[row];
            const float* src = Ev + (size_t)x * DIM + d0;
            #pragma unroll
            for (int c8 = 0; c8 < 4; ++c8) {
                bfrag h, l;
                split8(src + c8 * 8, h, l);
                *reinterpret_cast<bfrag*>(&shi[rts][ms][d0 + c8 * 8]) = h;
                *reinterpret_cast<bfrag*>(&slo[rts][ms][d0 + c8 * 8]) = l;
            }
        }
        __syncthreads();

        #pragma unroll
        for (int dt = 0; dt < 2; ++dt) {
            const int n = (wv * 2 + dt) * 16 + nloc;
            bfrag Beh[4], Bel[4], Bah[4], Bal[4];
            #pragma unroll
            for (int kc = 0; kc < 4; ++kc) {
                const int ko = kc * 32 + quad * 8;
                Beh[kc] = *reinterpret_cast<const bfrag*>(weT_hi + n * DIM + ko);
                Bel[kc] = *reinterpret_cast<const bfrag*>(weT_lo + n * DIM + ko);
                Bah[kc] = *reinterpret_cast<const bfrag*>(waT_hi + n * DIM + ko);
                Bal[kc] = *reinterpret_cast<const bfrag*>(waT_lo + n * DIM + ko);
            }
            f32x4 acc_e[4], acc_a[4];
            #pragma unroll
            for (int t = 0; t < 4; ++t) { acc_e[t] = 0.f; acc_a[t] = 0.f; }

            #pragma unroll
            for (int rt = 0; rt < 4; ++rt) {
                #pragma unroll
                for (int kc = 0; kc < 4; ++kc) {
                    const int ko = kc * 32 + quad * 8;
                    bfrag Ah = *reinterpret_cast<const bfrag*>(&shi[rt][nloc][ko]);
                    bfrag Al = *reinterpret_cast<const bfrag*>(&slo[rt][nloc][ko]);
                    acc_e[rt] = __builtin_amdgcn_mfma_f32_16x16x32_bf16(Ah, Beh[kc], acc_e[rt], 0, 0, 0);
                    acc_a[rt] = __builtin_amdgcn_mfma_f32_16x16x32_bf16(Ah, Bah[kc], acc_a[rt], 0, 0, 0);
                    acc_e[rt] = __builtin_amdgcn_mfma_f32_16x16x32_bf16(Ah, Bel[kc], acc_e[rt], 0, 0, 0);
                    acc_a[rt] = __builtin_amdgcn_mfma_f32_16x16x32_bf16(Ah, Bal[kc], acc_a[rt], 0, 0, 0);
                    acc_e[rt] = __builtin_amdgcn_mfma_f32_16x16x32_bf16(Al, Beh[kc], acc_e[rt], 0, 0, 0);
                    acc_a[rt] = __builtin_amdgcn_mfma_f32_16x16x32_bf16(Al, Bah[kc], acc_a[rt], 0, 0, 0);
                }
            }
            const float bev = be[n], bav = ba[n];
            #pragma unroll
            for (int rt = 0; rt < 4; ++rt) {
                #pragma unroll
                for (int rg = 0; rg < 4; ++rg) {
                    const int row = base + rt * 16 + quad * 4 + rg;
                    float2 ea;
                    ea.x = sigmoidf_fast(acc_e[rt][rg] + bev);
                    ea.y = tanhf_fast(acc_a[rt][rg] + bav);
                    ea_out[(size_t)row * DIM + n] = ea;
                }
            }
        }
    }
}

// ---------------------------------------------------------------------------
// Kernel C: scan, async-DMA LDS tiles, 2 waves/SIMD.
// Grid (ds=8, b=64) = 512 blocks, 256 thr. Thread: p = tid&15 owns 4 m
// (m0 = p*4); dl = tid>>4 -> d = ds*16 + dl (16 d per block).
// Per step: 2 ds_reads + 12 FMA + xor1/xor2 DPP -> quad-sums; lanes with
// p%4==0 store 4 quarter-sums to rd4[b][t][d][p>>2]; kD sums the float4.
// ---------------------------------------------------------------------------
__device__ __forceinline__ void scan32(const float* wb, const float2* eab,
                                       int m0, int dl, int p, int t0,
                                       float (&Mv)[4], float* rp4) {
    #pragma unroll
    for (int u = 0; u < 32; ++u) {
        float4 w4 = *reinterpret_cast<const float4*>(wb + u * 64 + m0);
        float2 ea = eab[u * 16 + dl];
        float wv[4] = {w4.x, w4.y, w4.z, w4.w};
        float e_c = ea.x, a_c = ea.y;
        float part = 0.f;
        #pragma unroll
        for (int j = 0; j < 4; ++j) {
            float old = Mv[j];
            part = fmaf(wv[j], old, part);                   // read BEFORE update
            Mv[j] = fmaf(wv[j], fmaf(-old, e_c, a_c), old);
        }
        part += quad_swap1(part);
        part += quad_swap2(part);     // all lanes in quad hold quad-sum
        if ((p & 3) == 0)             // p in {0,4,8,12} -> quarter p>>2
            rp4[(size_t)(t0 + u) * (DIM * 4)] = part;
    }
}

__global__ __launch_bounds__(256) void kC(const float* __restrict__ Mv0,
                                          const float* __restrict__ w_in,
                                          const float2* __restrict__ ea_in,
                                          float* __restrict__ rd4) {
    __shared__ __align__(16) float  wlds[2][32][64];    // 16 KB
    __shared__ __align__(16) float2 ealds[2][32][16];   // 8 KB
    const int tid = threadIdx.x;
    const int lane = tid & 63;
    const int wvid = tid >> 6;
    const int p = tid & 15;
    const int dl = tid >> 4;
    const int ds = blockIdx.x, b = blockIdx.y;
    const int d = ds * 16 + dl;
    const int m0 = p * 4;

    const char* wsrc  = (const char*)(w_in + (size_t)b * LL * MM);
    const char* easrc = (const char*)(ea_in + (size_t)b * LL * DIM + ds * 16);
    float* rp4 = rd4 + (size_t)b * LL * (DIM * 4) + (size_t)d * 4 + (p >> 2);

    auto dma = [&](int c, int bufi) {
        const char* wt = wsrc + (size_t)c * 8192;
        char* wl = (char*)&wlds[bufi][0][0];
        char* el = (char*)&ealds[bufi][0][0];
        #pragma unroll
        for (int i = 0; i < 2; ++i) {
            const int off = wvid * 2048 + i * 1024 + lane * 16;
            ld16(wt + off, wl + off);
        }
        const int off2 = wvid * 1024 + lane * 16;         // 0..4095
        const int tl = off2 >> 7, wi = off2 & 127;        // 128B ea rows
        ld16(easrc + (size_t)(c * 32 + tl) * (DIM * 8) + wi, el + off2);
    };

    dma(0, 0);

    float Mv[4];
    #pragma unroll
    for (int j = 0; j < 4; ++j)
        Mv[j] = Mv0[(m0 + j) * DIM + d];

    __builtin_amdgcn_s_waitcnt(0x0F70);   // vmcnt(0): tile-0 DMA + Mv loads done
    __syncthreads();

    int buf = 0;
    for (int c = 0; c < LL / 32; ++c) {
        if (c + 1 < LL / 32) dma(c + 1, buf ^ 1);
        scan32(&wlds[buf][0][0], &ealds[buf][0][0], m0, dl, p, c * 32, Mv, rp4);
        if (c + 1 < LL / 32) {
            // FIFO: [old stores][3 DMA][32 new stores]; vmcnt(32) retires
            // through the DMAs without draining the newest stores.
            __builtin_amdgcn_s_waitcnt(0x8F70);   // vmcnt(32)
            __syncthreads();
            buf ^= 1;
        }
    }
}

// ---------------------------------------------------------------------------
// Kernel D (MFMA): read[d] = sum of rd4[row][d][0..3]; f = tanh([read,k]@Wf+bf);
// p = sigmoid(f@Wp+bp). 64 rows/block.
// ---------------------------------------------------------------------------
__global__ __launch_bounds__(256) void kD(const int* __restrict__ q,
                                          const float* __restrict__ Ek,
                                          const u16* __restrict__ wfT_hi, const u16* __restrict__ wfT_lo,
                                          const float* __restrict__ bfv,
                                          const float* __restrict__ Wp, const float* __restrict__ bp,
                                          const float* __restrict__ rd4,
                                          float* __restrict__ out) {
    __shared__ __align__(16) u16 xhi[4][16][264];
    __shared__ __align__(16) u16 xlo[4][16][264];
    __shared__ float sred[64][4];
    const int tid = threadIdx.x;
    const int base = blockIdx.x * 64;
    const int row_l = tid >> 2;
    const int rts = row_l >> 4, ms = row_l & 15;
    const int d0 = (tid & 3) * 32;
    const int row = base + row_l;

    {   // x[:, 0:128) = read (sum of 4 stored quarter-sums per d)
        const float4* src4 = reinterpret_cast<const float4*>(rd4 + (size_t)row * (DIM * 4)) + d0;
        #pragma unroll
        for (int c8 = 0; c8 < 4; ++c8) {
            float xs[8];
            #pragma unroll
            for (int j = 0; j < 8; ++j) {
                float4 v = src4[c8 * 8 + j];
                xs[j] = (v.x + v.y) + (v.z + v.w);
            }
            bfrag h, l;
            #pragma unroll
            for (int j = 0; j < 8; ++j) {
                u16 hb = f2bf(xs[j]);
                h[j] = (short)hb;
                l[j] = (short)f2bf(xs[j] - bf2f(hb));
            }
            *reinterpret_cast<bfrag*>(&xhi[rts][ms][d0 + c8 * 8]) = h;
            *reinterpret_cast<bfrag*>(&xlo[rts][ms][d0 + c8 * 8]) = l;
        }
    }
    {   // x[:, 128:256) = Ek[q[row]]
        const float* src = Ek + (size_t)q[row] * DIM + d0;
        #pragma unroll
        for (int c8 = 0; c8 < 4; ++c8) {
            bfrag h, l;
            split8(src + c8 * 8, h, l);
            *reinterpret_cast<bfrag*>(&xhi[rts][ms][128 + d0 + c8 * 8]) = h;
            *reinterpret_cast<bfrag*>(&xlo[rts][ms][128 + d0 + c8 * 8]) = l;
        }
    }
    __syncthreads();

    const int lane = tid & 63;
    const int wv = tid >> 6;
    const int nloc = lane & 15;
    const int quad = lane >> 4;
    float* fbuf = reinterpret_cast<float*>(&xhi[0][0][0]);   // overlay after sync

    f32x4 acc[2][4];
    #pragma unroll
    for (int dt = 0; dt < 2; ++dt)
        #pragma unroll
        for (int t = 0; t < 4; ++t) acc[dt][t] = 0.f;

    #pragma unroll
    for (int dt = 0; dt < 2; ++dt) {
        const int n = (wv * 2 + dt) * 16 + nloc;
        bfrag Bh[8], Bl[8];
        #pragma unroll
        for (int kc = 0; kc < 8; ++kc) {
            const int ko = kc * 32 + quad * 8;
            Bh[kc] = *reinterpret_cast<const bfrag*>(wfT_hi + n * 256 + ko);
            Bl[kc] = *reinterpret_cast<const bfrag*>(wfT_lo + n * 256 + ko);
        }
        #pragma unroll
        for (int rt = 0; rt < 4; ++rt) {
            #pragma unroll
            for (int kc = 0; kc < 8; ++kc) {
                const int ko = kc * 32 + quad * 8;
                bfrag Ah = *reinterpret_cast<const bfrag*>(&xhi[rt][nloc][ko]);
                bfrag Al = *reinterpret_cast<const bfrag*>(&xlo[rt][nloc][ko]);
                acc[dt][rt] = __builtin_amdgcn_mfma_f32_16x16x32_bf16(Ah, Bh[kc], acc[dt][rt], 0, 0, 0);
                acc[dt][rt] = __builtin_amdgcn_mfma_f32_16x16x32_bf16(Ah, Bl[kc], acc[dt][rt], 0, 0, 0);
                acc[dt][rt] = __builtin_amdgcn_mfma_f32_16x16x32_bf16(Al, Bh[kc], acc[dt][rt], 0, 0, 0);
            }
        }
    }
    __syncthreads();   // LDS x reads done before fbuf overlay

    #pragma unroll
    for (int dt = 0; dt < 2; ++dt) {
        const int n = (wv * 2 + dt) * 16 + nloc;
        const float bfn = bfv[n], wpn = Wp[n];
        #pragma unroll
        for (int rt = 0; rt < 4; ++rt)
            #pragma unroll
            for (int rg = 0; rg < 4; ++rg)
                fbuf[(rt * 16 + quad * 4 + rg) * 132 + n] = tanhf_fast(acc[dt][rt][rg] + bfn) * wpn;
    }
    __syncthreads();

    {
        float s = 0.f;
        const int c = tid & 3;
        #pragma unroll
        for (int k = 0; k < 32; ++k) s += fbuf[row_l * 132 + c * 32 + k];
        sred[row_l][c] = s;
    }
    __syncthreads();
    if (tid < 64)
        out[base + tid] = sigmoidf_fast(sred[tid][0] + sred[tid][1] + sred[tid][2] + sred[tid][3] + bp[0]);
}

// ---------------------------------------------------------------------------
extern "C" void kernel_launch(void* const* d_in, const int* in_sizes, int n_in,
                              void* d_out, int out_size, void* d_ws, size_t ws_size,
                              hipStream_t stream) {
    const int*   q   = (const int*)d_in[0];
    const int*   r   = (const int*)d_in[1];
    const float* Ek  = (const float*)d_in[2];
    const float* Ev  = (const float*)d_in[3];
    const float* Mk  = (const float*)d_in[4];
    const float* Mv0 = (const float*)d_in[5];
    const float* We  = (const float*)d_in[6];
    const float* be  = (const float*)d_in[7];
    const float* Wa  = (const float*)d_in[8];
    const float* ba  = (const float*)d_in[9];
    const float* Wf  = (const float*)d_in[10];
    const float* bfv = (const float*)d_in[11];
    const float* Wp  = (const float*)d_in[12];
    const float* bp  = (const float*)d_in[13];
    float* out = (float*)d_out;

    float*  ws     = (float*)d_ws;
    float*  w_buf  = ws;                                      // 8 MB
    float2* ea_buf = (float2*)(w_buf + (size_t)NROWS * MM);   // 32 MB
    float*  rd4    = (float*)(ea_buf + (size_t)NROWS * DIM);  // 64 MB (4 quarters)

    // prepped bf16 weights at the END of ws (288 KB)
    size_t prep_off = (ws_size - (size_t)294912) & ~(size_t)255;
    u16* weT_hi = (u16*)((char*)d_ws + prep_off);
    u16* weT_lo = weT_hi + 16384;
    u16* waT_hi = weT_lo + 16384;
    u16* waT_lo = waT_hi + 16384;
    u16* wfT_hi = waT_lo + 16384;
    u16* wfT_lo = wfT_hi + 32768;
    u16* mkT_hi = wfT_lo + 32768;
    u16* mkT_lo = mkT_hi + 8192;

    kP<<<dim3(128), 256, 0, stream>>>(We, Wa, Wf, Mk, weT_hi, weT_lo, waT_hi, waT_lo,
                                      wfT_hi, wfT_lo, mkT_hi, mkT_lo);
    kAB<<<dim3(1024), 256, 0, stream>>>(q, r, Ek, Ev, mkT_hi, mkT_lo,
                                        weT_hi, weT_lo, waT_hi, waT_lo,
                                        be, ba, w_buf, ea_buf);
    kC<<<dim3(8, BB), 256, 0, stream>>>(Mv0, w_buf, ea_buf, rd4);
    kD<<<dim3(NROWS / 64), 256, 0, stream>>>(q, Ek, wfT_hi, wfT_lo, bfv, Wp, bp, rd4, out);
}

// Round 14
// 180.372 us; speedup vs baseline: 1.3391x; 1.0127x over previous
//
#include <hip/hip_runtime.h>
#include <hip/hip_bf16.h>

#define NUM_C 1000
#define DIM   128
#define MM    64
#define BB    64
#define LL    512
#define NROWS (BB * LL)   // 32768

typedef unsigned short u16;
typedef unsigned int   u32;
typedef short bfrag __attribute__((ext_vector_type(8)));   // 8 bf16 (4 VGPRs)
typedef float f32x4 __attribute__((ext_vector_type(4)));   // MFMA acc

__device__ __forceinline__ float sigmoidf_fast(float x) { return 1.f / (1.f + __expf(-x)); }
__device__ __forceinline__ float tanhf_fast(float x) { return 1.f - 2.f / (__expf(2.f * x) + 1.f); }

__device__ __forceinline__ u16 f2bf(float x) {            // RNE f32->bf16 bits
    u32 u = __float_as_uint(x);
    return (u16)((u + 0x7FFFu + ((u >> 16) & 1u)) >> 16);
}
__device__ __forceinline__ float bf2f(u16 h) { return __uint_as_float(((u32)h) << 16); }

// DPP quad_perm swaps (VALU-only, verified rounds 5-13)
__device__ __forceinline__ float quad_swap1(float x) {
    return __int_as_float(__builtin_amdgcn_mov_dpp(__float_as_int(x), 0xB1, 0xF, 0xF, true));
}
__device__ __forceinline__ float quad_swap2(float x) {
    return __int_as_float(__builtin_amdgcn_mov_dpp(__float_as_int(x), 0x4E, 0xF, 0xF, true));
}
// DPP row rotate-right within rows of 16 (VALU-only): ring all-reduce steps
__device__ __forceinline__ float row_ror4(float x) {
    return __int_as_float(__builtin_amdgcn_mov_dpp(__float_as_int(x), 0x124, 0xF, 0xF, true));
}
__device__ __forceinline__ float row_ror8(float x) {
    return __int_as_float(__builtin_amdgcn_mov_dpp(__float_as_int(x), 0x128, 0xF, 0xF, true));
}

// async global->LDS DMA, 16B per lane, LDS dest = wave-uniform base + lane*16
__device__ __forceinline__ void ld16(const void* g, void* l) {
    __builtin_amdgcn_global_load_lds(
        (const __attribute__((address_space(1))) unsigned int*)g,
        (__attribute__((address_space(3))) unsigned int*)l, 16, 0, 0);
}

// ---------------------------------------------------------------------------
// Prep: bf16 hi/lo weights. weT/waT [n][k], wfT [n][k] (transposed), mkT = Mk.
// ---------------------------------------------------------------------------
__global__ __launch_bounds__(256) void kP(const float* __restrict__ We,
                                          const float* __restrict__ Wa,
                                          const float* __restrict__ Wf,
                                          const float* __restrict__ Mk,
                                          u16* weT_hi, u16* weT_lo,
                                          u16* waT_hi, u16* waT_lo,
                                          u16* wfT_hi, u16* wfT_lo,
                                          u16* mkT_hi, u16* mkT_lo) {
    int idx = blockIdx.x * 256 + threadIdx.x;   // 0..32767
    if (idx < 128 * 128) {
        int n = idx >> 7, k = idx & 127;
        float we = We[k * DIM + n];
        u16 h = f2bf(we);
        weT_hi[idx] = h; weT_lo[idx] = f2bf(we - bf2f(h));
        float wa = Wa[k * DIM + n];
        u16 h2 = f2bf(wa);
        waT_hi[idx] = h2; waT_lo[idx] = f2bf(wa - bf2f(h2));
    }
    if (idx < 64 * 128) {
        float mk = Mk[idx];
        u16 h = f2bf(mk);
        mkT_hi[idx] = h; mkT_lo[idx] = f2bf(mk - bf2f(h));
    }
    {
        int n = idx >> 8, k = idx & 255;
        float wf = Wf[k * DIM + n];
        u16 h = f2bf(wf);
        wfT_hi[idx] = h; wfT_lo[idx] = f2bf(wf - bf2f(h));
    }
}

// helper: split float8 chunk to bf16 hi/lo frags
__device__ __forceinline__ void split8(const float* src, bfrag& h, bfrag& l) {
    float4 f0 = *reinterpret_cast<const float4*>(src);
    float4 f1 = *reinterpret_cast<const float4*>(src + 4);
    float xs[8] = {f0.x, f0.y, f0.z, f0.w, f1.x, f1.y, f1.z, f1.w};
    #pragma unroll
    for (int j = 0; j < 8; ++j) {
        u16 hb = f2bf(xs[j]);
        h[j] = (short)hb;
        l[j] = (short)f2bf(xs[j] - bf2f(hb));
    }
}

// ---------------------------------------------------------------------------
// Fused kAB (MFMA). Blocks [0,512): kA role -> w = softmax(Ek[q].Mk^T).
// Blocks [512,1024): kB role -> e/a = sig/tanh(Ev[x]@We|Wa), float2 out.
// ---------------------------------------------------------------------------
__global__ __launch_bounds__(256) void kAB(const int* __restrict__ q,
                                           const int* __restrict__ r,
                                           const float* __restrict__ Ek,
                                           const float* __restrict__ Ev,
                                           const u16* __restrict__ mkT_hi, const u16* __restrict__ mkT_lo,
                                           const u16* __restrict__ weT_hi, const u16* __restrict__ weT_lo,
                                           const u16* __restrict__ waT_hi, const u16* __restrict__ waT_lo,
                                           const float* __restrict__ be, const float* __restrict__ ba,
                                           float* __restrict__ w_out,
                                           float2* __restrict__ ea_out) {
    __shared__ __align__(16) u16 shi[4][16][136];
    __shared__ __align__(16) u16 slo[4][16][136];
    __shared__ float slab[4][64];
    const int tid = threadIdx.x;
    const int lane = tid & 63;
    const int wv = tid >> 6;
    const int nloc = lane & 15;
    const int quad = lane >> 4;

    if (blockIdx.x < 512) {
        // ---------------- kA role ----------------
        const int base = blockIdx.x * 64;
        {   // stage k = Ek[q] as bf16 hi/lo
            const int row_l = tid >> 2;
            const int rts = row_l >> 4, ms = row_l & 15;
            const int d0 = (tid & 3) * 32;
            const float* src = Ek + (size_t)q[base + row_l] * DIM + d0;
            #pragma unroll
            for (int c8 = 0; c8 < 4; ++c8) {
                bfrag h, l;
                split8(src + c8 * 8, h, l);
                *reinterpret_cast<bfrag*>(&shi[rts][ms][d0 + c8 * 8]) = h;
                *reinterpret_cast<bfrag*>(&slo[rts][ms][d0 + c8 * 8]) = l;
            }
        }
        __syncthreads();

        const int n = wv * 16 + nloc;      // m index
        bfrag Bh[4], Bl[4];
        #pragma unroll
        for (int kc = 0; kc < 4; ++kc) {
            const int ko = kc * 32 + quad * 8;
            Bh[kc] = *reinterpret_cast<const bfrag*>(mkT_hi + n * DIM + ko);
            Bl[kc] = *reinterpret_cast<const bfrag*>(mkT_lo + n * DIM + ko);
        }

        f32x4 acc[4];
        #pragma unroll
        for (int t = 0; t < 4; ++t) acc[t] = 0.f;

        #pragma unroll
        for (int rt = 0; rt < 4; ++rt) {
            #pragma unroll
            for (int kc = 0; kc < 4; ++kc) {
                const int ko = kc * 32 + quad * 8;
                bfrag Ah = *reinterpret_cast<const bfrag*>(&shi[rt][nloc][ko]);
                bfrag Al = *reinterpret_cast<const bfrag*>(&slo[rt][nloc][ko]);
                acc[rt] = __builtin_amdgcn_mfma_f32_16x16x32_bf16(Ah, Bh[kc], acc[rt], 0, 0, 0);
                acc[rt] = __builtin_amdgcn_mfma_f32_16x16x32_bf16(Ah, Bl[kc], acc[rt], 0, 0, 0);
                acc[rt] = __builtin_amdgcn_mfma_f32_16x16x32_bf16(Al, Bh[kc], acc[rt], 0, 0, 0);
            }
        }

        float ex[4][4];
        #pragma unroll
        for (int rt = 0; rt < 4; ++rt) {
            #pragma unroll
            for (int rg = 0; rg < 4; ++rg) {
                float e = __expf(acc[rt][rg]);
                ex[rt][rg] = e;
                float s = e;
                s += __shfl_xor(s, 1);
                s += __shfl_xor(s, 2);
                s += __shfl_xor(s, 4);
                s += __shfl_xor(s, 8);
                if (nloc == 0) slab[wv][rt * 16 + quad * 4 + rg] = s;
            }
        }
        __syncthreads();

        #pragma unroll
        for (int rt = 0; rt < 4; ++rt) {
            #pragma unroll
            for (int rg = 0; rg < 4; ++rg) {
                const int row = rt * 16 + quad * 4 + rg;
                float tot = slab[0][row] + slab[1][row] + slab[2][row] + slab[3][row];
                w_out[(size_t)(base + row) * MM + n] = ex[rt][rg] / tot;
            }
        }
    } else {
        // ---------------- kB role ----------------
        const int base = (blockIdx.x - 512) * 64;
        {   // stage v = Ev[x] as bf16 hi/lo
            const int row_l = tid >> 2;
            const int rts = row_l >> 4, ms = row_l & 15;
            const int d0 = (tid & 3) * 32;
            const int row = base + row_l;
            const int x = q[row] + NUM_C * r[row];
            const float* src = Ev + (size_t)x * DIM + d0;
            #pragma unroll
            for (int c8 = 0; c8 < 4; ++c8) {
                bfrag h, l;
                split8(src + c8 * 8, h, l);
                *reinterpret_cast<bfrag*>(&shi[rts][ms][d0 + c8 * 8]) = h;
                *reinterpret_cast<bfrag*>(&slo[rts][ms][d0 + c8 * 8]) = l;
            }
        }
        __syncthreads();

        #pragma unroll
        for (int dt = 0; dt < 2; ++dt) {
            const int n = (wv * 2 + dt) * 16 + nloc;
            bfrag Beh[4], Bel[4], Bah[4], Bal[4];
            #pragma unroll
            for (int kc = 0; kc < 4; ++kc) {
                const int ko = kc * 32 + quad * 8;
                Beh[kc] = *reinterpret_cast<const bfrag*>(weT_hi + n * DIM + ko);
                Bel[kc] = *reinterpret_cast<const bfrag*>(weT_lo + n * DIM + ko);
                Bah[kc] = *reinterpret_cast<const bfrag*>(waT_hi + n * DIM + ko);
                Bal[kc] = *reinterpret_cast<const bfrag*>(waT_lo + n * DIM + ko);
            }
            f32x4 acc_e[4], acc_a[4];
            #pragma unroll
            for (int t = 0; t < 4; ++t) { acc_e[t] = 0.f; acc_a[t] = 0.f; }

            #pragma unroll
            for (int rt = 0; rt < 4; ++rt) {
                #pragma unroll
                for (int kc = 0; kc < 4; ++kc) {
                    const int ko = kc * 32 + quad * 8;
                    bfrag Ah = *reinterpret_cast<const bfrag*>(&shi[rt][nloc][ko]);
                    bfrag Al = *reinterpret_cast<const bfrag*>(&slo[rt][nloc][ko]);
                    acc_e[rt] = __builtin_amdgcn_mfma_f32_16x16x32_bf16(Ah, Beh[kc], acc_e[rt], 0, 0, 0);
                    acc_a[rt] = __builtin_amdgcn_mfma_f32_16x16x32_bf16(Ah, Bah[kc], acc_a[rt], 0, 0, 0);
                    acc_e[rt] = __builtin_amdgcn_mfma_f32_16x16x32_bf16(Ah, Bel[kc], acc_e[rt], 0, 0, 0);
                    acc_a[rt] = __builtin_amdgcn_mfma_f32_16x16x32_bf16(Ah, Bal[kc], acc_a[rt], 0, 0, 0);
                    acc_e[rt] = __builtin_amdgcn_mfma_f32_16x16x32_bf16(Al, Beh[kc], acc_e[rt], 0, 0, 0);
                    acc_a[rt] = __builtin_amdgcn_mfma_f32_16x16x32_bf16(Al, Bah[kc], acc_a[rt], 0, 0, 0);
                }
            }
            const float bev = be[n], bav = ba[n];
            #pragma unroll
            for (int rt = 0; rt < 4; ++rt) {
                #pragma unroll
                for (int rg = 0; rg < 4; ++rg) {
                    const int row = base + rt * 16 + quad * 4 + rg;
                    float2 ea;
                    ea.x = sigmoidf_fast(acc_e[rt][rg] + bev);
                    ea.y = tanhf_fast(acc_a[rt][rg] + bav);
                    ea_out[(size_t)row * DIM + n] = ea;
                }
            }
        }
    }
}

// ---------------------------------------------------------------------------
// Kernel C: scan, async-DMA LDS tiles, 2 waves/SIMD, FULL in-wave m-reduce.
// Grid (ds=4, b=64) = 256 blocks, 512 thr (8 waves). Thread: p = tid&15 owns
// 4 m (m0 = p*4); dl = tid>>4 -> d = ds*32 + dl (32 d per block).
// Reduce: quad xor1+xor2 -> quad-sums, then DPP row_ror4+ror8 ring-adds ->
// every lane holds the full 64-m sum; lane p==0 stores ONE f32 to rd[b][t][d].
// w read 4x (was 8x), rd write 16 MB (was 64). All VALU; no LDS-pipe reduce.
// ---------------------------------------------------------------------------
__device__ __forceinline__ void scan32(const float* wb, const float2* eab,
                                       int m0, int dl, int p, int t0,
                                       float (&Mv)[4], float* rp) {
    #pragma unroll
    for (int u = 0; u < 32; ++u) {
        float4 w4 = *reinterpret_cast<const float4*>(wb + u * 64 + m0);
        float2 ea = eab[u * 32 + dl];
        float wv[4] = {w4.x, w4.y, w4.z, w4.w};
        float e_c = ea.x, a_c = ea.y;
        float part = 0.f;
        #pragma unroll
        for (int j = 0; j < 4; ++j) {
            float old = Mv[j];
            part = fmaf(wv[j], old, part);                   // read BEFORE update
            Mv[j] = fmaf(wv[j], fmaf(-old, e_c, a_c), old);
        }
        part += quad_swap1(part);
        part += quad_swap2(part);     // quad sums
        part += row_ror4(part);       // + next quad's sum
        part += row_ror8(part);       // + remaining two -> full 16-lane total
        if (p == 0) rp[(size_t)(t0 + u) * DIM] = part;
    }
}

__global__ __launch_bounds__(512) void kC(const float* __restrict__ Mv0,
                                          const float* __restrict__ w_in,
                                          const float2* __restrict__ ea_in,
                                          float* __restrict__ rd) {
    __shared__ __align__(16) float  wlds[2][32][64];    // 16 KB
    __shared__ __align__(16) float2 ealds[2][32][32];   // 16 KB
    const int tid = threadIdx.x;
    const int lane = tid & 63;
    const int wvid = tid >> 6;        // 0..7
    const int p = tid & 15;
    const int dl = tid >> 4;          // 0..31
    const int ds = blockIdx.x, b = blockIdx.y;
    const int d = ds * 32 + dl;
    const int m0 = p * 4;

    const char* wsrc  = (const char*)(w_in + (size_t)b * LL * MM);
    const char* easrc = (const char*)(ea_in + (size_t)b * LL * DIM + ds * 32);
    float* rp = rd + (size_t)b * LL * DIM + d;

    auto dma = [&](int c, int bufi) {
        const char* wt = wsrc + (size_t)c * 8192;
        char* wl = (char*)&wlds[bufi][0][0];
        char* el = (char*)&ealds[bufi][0][0];
        const int off = wvid * 1024 + lane * 16;          // 0..8191
        ld16(wt + off, wl + off);                         // w: contiguous 8 KB
        const int tl = off >> 8, wi = off & 255;          // ea: 256B rows, 1KB stride
        ld16(easrc + (size_t)(c * 32 + tl) * (DIM * 8) + wi, el + off);
    };

    dma(0, 0);

    float Mv[4];
    #pragma unroll
    for (int j = 0; j < 4; ++j)
        Mv[j] = Mv0[(m0 + j) * DIM + d];

    __builtin_amdgcn_s_waitcnt(0x0F70);   // vmcnt(0): tile-0 DMA + Mv loads done
    __syncthreads();

    int buf = 0;
    for (int c = 0; c < LL / 32; ++c) {
        if (c + 1 < LL / 32) dma(c + 1, buf ^ 1);
        scan32(&wlds[buf][0][0], &ealds[buf][0][0], m0, dl, p, c * 32, Mv, rp);
        if (c + 1 < LL / 32) {
            // Per wave FIFO: [old stores][2 DMA][32 new stores]; vmcnt(32)
            // retires through the DMAs without draining the newest stores.
            __builtin_amdgcn_s_waitcnt(0x8F70);   // vmcnt(32)
            __syncthreads();
            buf ^= 1;
        }
    }
}

// ---------------------------------------------------------------------------
// Kernel D (MFMA): f = tanh([rd,k]@Wf+bf); p = sigmoid(f@Wp+bp). 64 rows/blk.
// ---------------------------------------------------------------------------
__global__ __launch_bounds__(256) void kD(const int* __restrict__ q,
                                          const float* __restrict__ Ek,
                                          const u16* __restrict__ wfT_hi, const u16* __restrict__ wfT_lo,
                                          const float* __restrict__ bfv,
                                          const float* __restrict__ Wp, const float* __restrict__ bp,
                                          const float* __restrict__ rd,
                                          float* __restrict__ out) {
    __shared__ __align__(16) u16 xhi[4][16][264];
    __shared__ __align__(16) u16 xlo[4][16][264];
    __shared__ float sred[64][4];
    const int tid = threadIdx.x;
    const int base = blockIdx.x * 64;
    const int row_l = tid >> 2;
    const int rts = row_l >> 4, ms = row_l & 15;
    const int d0 = (tid & 3) * 32;
    const int row = base + row_l;

    {   // x[:, 0:128) = rd (already fully reduced)
        const float* src = rd + (size_t)row * DIM + d0;
        #pragma unroll
        for (int c8 = 0; c8 < 4; ++c8) {
            bfrag h, l;
            split8(src + c8 * 8, h, l);
            *reinterpret_cast<bfrag*>(&xhi[rts][ms][d0 + c8 * 8]) = h;
            *reinterpret_cast<bfrag*>(&xlo[rts][ms][d0 + c8 * 8]) = l;
        }
    }
    {   // x[:, 128:256) = Ek[q[row]]
        const float* src = Ek + (size_t)q[row] * DIM + d0;
        #pragma unroll
        for (int c8 = 0; c8 < 4; ++c8) {
            bfrag h, l;
            split8(src + c8 * 8, h, l);
            *reinterpret_cast<bfrag*>(&xhi[rts][ms][128 + d0 + c8 * 8]) = h;
            *reinterpret_cast<bfrag*>(&xlo[rts][ms][128 + d0 + c8 * 8]) = l;
        }
    }
    __syncthreads();

    const int lane = tid & 63;
    const int wv = tid >> 6;
    const int nloc = lane & 15;
    const int quad = lane >> 4;
    float* fbuf = reinterpret_cast<float*>(&xhi[0][0][0]);   // overlay after sync

    f32x4 acc[2][4];
    #pragma unroll
    for (int dt = 0; dt < 2; ++dt)
        #pragma unroll
        for (int t = 0; t < 4; ++t) acc[dt][t] = 0.f;

    #pragma unroll
    for (int dt = 0; dt < 2; ++dt) {
        const int n = (wv * 2 + dt) * 16 + nloc;
        bfrag Bh[8], Bl[8];
        #pragma unroll
        for (int kc = 0; kc < 8; ++kc) {
            const int ko = kc * 32 + quad * 8;
            Bh[kc] = *reinterpret_cast<const bfrag*>(wfT_hi + n * 256 + ko);
            Bl[kc] = *reinterpret_cast<const bfrag*>(wfT_lo + n * 256 + ko);
        }
        #pragma unroll
        for (int rt = 0; rt < 4; ++rt) {
            #pragma unroll
            for (int kc = 0; kc < 8; ++kc) {
                const int ko = kc * 32 + quad * 8;
                bfrag Ah = *reinterpret_cast<const bfrag*>(&xhi[rt][nloc][ko]);
                bfrag Al = *reinterpret_cast<const bfrag*>(&xlo[rt][nloc][ko]);
                acc[dt][rt] = __builtin_amdgcn_mfma_f32_16x16x32_bf16(Ah, Bh[kc], acc[dt][rt], 0, 0, 0);
                acc[dt][rt] = __builtin_amdgcn_mfma_f32_16x16x32_bf16(Ah, Bl[kc], acc[dt][rt], 0, 0, 0);
                acc[dt][rt] = __builtin_amdgcn_mfma_f32_16x16x32_bf16(Al, Bh[kc], acc[dt][rt], 0, 0, 0);
            }
        }
    }
    __syncthreads();   // LDS x reads done before fbuf overlay

    #pragma unroll
    for (int dt = 0; dt < 2; ++dt) {
        const int n = (wv * 2 + dt) * 16 + nloc;
        const float bfn = bfv[n], wpn = Wp[n];
        #pragma unroll
        for (int rt = 0; rt < 4; ++rt)
            #pragma unroll
            for (int rg = 0; rg < 4; ++rg)
                fbuf[(rt * 16 + quad * 4 + rg) * 132 + n] = tanhf_fast(acc[dt][rt][rg] + bfn) * wpn;
    }
    __syncthreads();

    {
        float s = 0.f;
        const int c = tid & 3;
        #pragma unroll
        for (int k = 0; k < 32; ++k) s += fbuf[row_l * 132 + c * 32 + k];
        sred[row_l][c] = s;
    }
    __syncthreads();
    if (tid < 64)
        out[base + tid] = sigmoidf_fast(sred[tid][0] + sred[tid][1] + sred[tid][2] + sred[tid][3] + bp[0]);
}

// ---------------------------------------------------------------------------
extern "C" void kernel_launch(void* const* d_in, const int* in_sizes, int n_in,
                              void* d_out, int out_size, void* d_ws, size_t ws_size,
                              hipStream_t stream) {
    const int*   q   = (const int*)d_in[0];
    const int*   r   = (const int*)d_in[1];
    const float* Ek  = (const float*)d_in[2];
    const float* Ev  = (const float*)d_in[3];
    const float* Mk  = (const float*)d_in[4];
    const float* Mv0 = (const float*)d_in[5];
    const float* We  = (const float*)d_in[6];
    const float* be  = (const float*)d_in[7];
    const float* Wa  = (const float*)d_in[8];
    const float* ba  = (const float*)d_in[9];
    const float* Wf  = (const float*)d_in[10];
    const float* bfv = (const float*)d_in[11];
    const float* Wp  = (const float*)d_in[12];
    const float* bp  = (const float*)d_in[13];
    float* out = (float*)d_out;

    float*  ws     = (float*)d_ws;
    float*  w_buf  = ws;                                      // 8 MB
    float2* ea_buf = (float2*)(w_buf + (size_t)NROWS * MM);   // 32 MB
    float*  rd     = (float*)(ea_buf + (size_t)NROWS * DIM);  // 16 MB

    // prepped bf16 weights at the END of ws (288 KB)
    size_t prep_off = (ws_size - (size_t)294912) & ~(size_t)255;
    u16* weT_hi = (u16*)((char*)d_ws + prep_off);
    u16* weT_lo = weT_hi + 16384;
    u16* waT_hi = weT_lo + 16384;
    u16* waT_lo = waT_hi + 16384;
    u16* wfT_hi = waT_lo + 16384;
    u16* wfT_lo = wfT_hi + 32768;
    u16* mkT_hi = wfT_lo + 32768;
    u16* mkT_lo = mkT_hi + 8192;

    kP<<<dim3(128), 256, 0, stream>>>(We, Wa, Wf, Mk, weT_hi, weT_lo, waT_hi, waT_lo,
                                      wfT_hi, wfT_lo, mkT_hi, mkT_lo);
    kAB<<<dim3(1024), 256, 0, stream>>>(q, r, Ek, Ev, mkT_hi, mkT_lo,
                                        weT_hi, weT_lo, waT_hi, waT_lo,
                                        be, ba, w_buf, ea_buf);
    kC<<<dim3(4, BB), 512, 0, stream>>>(Mv0, w_buf, ea_buf, rd);
    kD<<<dim3(NROWS / 64), 256, 0, stream>>>(q, Ek, wfT_hi, wfT_lo, bfv, Wp, bp, rd, out);
}

// Round 15
// 173.394 us; speedup vs baseline: 1.3930x; 1.0402x over previous
//
#include <hip/hip_runtime.h>
#include <hip/hip_bf16.h>

#define NUM_C 1000
#define DIM   128
#define MM    64
#define BB    64
#define LL    512
#define NROWS (BB * LL)   // 32768

typedef unsigned short u16;
typedef unsigned int   u32;
typedef short bfrag __attribute__((ext_vector_type(8)));   // 8 bf16 (4 VGPRs)
typedef float f32x4 __attribute__((ext_vector_type(4)));   // MFMA acc

__device__ __forceinline__ float sigmoidf_fast(float x) { return 1.f / (1.f + __expf(-x)); }
__device__ __forceinline__ float tanhf_fast(float x) { return 1.f - 2.f / (__expf(2.f * x) + 1.f); }

__device__ __forceinline__ u16 f2bf(float x) {            // RNE f32->bf16 bits
    u32 u = __float_as_uint(x);
    return (u16)((u + 0x7FFFu + ((u >> 16) & 1u)) >> 16);
}
__device__ __forceinline__ float bf2f(u16 h) { return __uint_as_float(((u32)h) << 16); }

// DPP quad_perm swaps + row rotates (VALU-only, verified rounds 5-14)
__device__ __forceinline__ float quad_swap1(float x) {
    return __int_as_float(__builtin_amdgcn_mov_dpp(__float_as_int(x), 0xB1, 0xF, 0xF, true));
}
__device__ __forceinline__ float quad_swap2(float x) {
    return __int_as_float(__builtin_amdgcn_mov_dpp(__float_as_int(x), 0x4E, 0xF, 0xF, true));
}
__device__ __forceinline__ float row_ror4(float x) {
    return __int_as_float(__builtin_amdgcn_mov_dpp(__float_as_int(x), 0x124, 0xF, 0xF, true));
}
__device__ __forceinline__ float row_ror8(float x) {
    return __int_as_float(__builtin_amdgcn_mov_dpp(__float_as_int(x), 0x128, 0xF, 0xF, true));
}

// async global->LDS DMA, 16B per lane, LDS dest = wave-uniform base + lane*16
__device__ __forceinline__ void ld16(const void* g, void* l) {
    __builtin_amdgcn_global_load_lds(
        (const __attribute__((address_space(1))) unsigned int*)g,
        (__attribute__((address_space(3))) unsigned int*)l, 16, 0, 0);
}

// ---------------------------------------------------------------------------
// Prep: B-side weights as bf16 hi/lo ([n][k] transposed); A-side embeddings
// Ek/Ev pre-converted to bf16 hi ONCE (removes per-row conversion in kAB/kD).
// ---------------------------------------------------------------------------
__global__ __launch_bounds__(256) void kP(const float* __restrict__ We,
                                          const float* __restrict__ Wa,
                                          const float* __restrict__ Wf,
                                          const float* __restrict__ Mk,
                                          const float* __restrict__ Ek,
                                          const float* __restrict__ Ev,
                                          u16* weT_hi, u16* weT_lo,
                                          u16* waT_hi, u16* waT_lo,
                                          u16* wfT_hi, u16* wfT_lo,
                                          u16* mkT_hi, u16* mkT_lo,
                                          u16* ekbf, u16* evbf) {
    int idx = blockIdx.x * 256 + threadIdx.x;   // 0..32767
    if (idx < 128 * 128) {
        int n = idx >> 7, k = idx & 127;
        float we = We[k * DIM + n];
        u16 h = f2bf(we);
        weT_hi[idx] = h; weT_lo[idx] = f2bf(we - bf2f(h));
        float wa = Wa[k * DIM + n];
        u16 h2 = f2bf(wa);
        waT_hi[idx] = h2; waT_lo[idx] = f2bf(wa - bf2f(h2));
    }
    if (idx < 64 * 128) {
        float mk = Mk[idx];
        u16 h = f2bf(mk);
        mkT_hi[idx] = h; mkT_lo[idx] = f2bf(mk - bf2f(h));
    }
    {
        int n = idx >> 8, k = idx & 255;
        float wf = Wf[k * DIM + n];
        u16 h = f2bf(wf);
        wfT_hi[idx] = h; wfT_lo[idx] = f2bf(wf - bf2f(h));
    }
    for (int i = idx; i < NUM_C * DIM; i += 32768) ekbf[i] = f2bf(Ek[i]);
    for (int i = idx; i < 2 * NUM_C * DIM; i += 32768) evbf[i] = f2bf(Ev[i]);
}

// ---------------------------------------------------------------------------
// Fused kAB (MFMA, A=bf16-hi only, B=hi+lo). Blocks [0,512): kA role.
// Blocks [512,1024): kB role. 64 rows/block; staging = pure u16 gather.
// ---------------------------------------------------------------------------
__global__ __launch_bounds__(256) void kAB(const int* __restrict__ q,
                                           const int* __restrict__ r,
                                           const u16* __restrict__ ekbf,
                                           const u16* __restrict__ evbf,
                                           const u16* __restrict__ mkT_hi, const u16* __restrict__ mkT_lo,
                                           const u16* __restrict__ weT_hi, const u16* __restrict__ weT_lo,
                                           const u16* __restrict__ waT_hi, const u16* __restrict__ waT_lo,
                                           const float* __restrict__ be, const float* __restrict__ ba,
                                           float* __restrict__ w_out,
                                           float2* __restrict__ ea_out) {
    __shared__ __align__(16) u16 shi[4][16][136];
    __shared__ float slab[4][64];
    const int tid = threadIdx.x;
    const int lane = tid & 63;
    const int wv = tid >> 6;
    const int nloc = lane & 15;
    const int quad = lane >> 4;

    if (blockIdx.x < 512) {
        // ---------------- kA role ----------------
        const int base = blockIdx.x * 64;
        {   // stage k = ekbf[q] (already bf16)
            const int row_l = tid >> 2;
            const int rts = row_l >> 4, ms = row_l & 15;
            const int d0 = (tid & 3) * 32;
            const u16* src = ekbf + (size_t)q[base + row_l] * DIM + d0;
            #pragma unroll
            for (int c8 = 0; c8 < 4; ++c8)
                *reinterpret_cast<bfrag*>(&shi[rts][ms][d0 + c8 * 8]) =
                    *reinterpret_cast<const bfrag*>(src + c8 * 8);
        }
        __syncthreads();

        const int n = wv * 16 + nloc;      // m index
        bfrag Bh[4], Bl[4];
        #pragma unroll
        for (int kc = 0; kc < 4; ++kc) {
            const int ko = kc * 32 + quad * 8;
            Bh[kc] = *reinterpret_cast<const bfrag*>(mkT_hi + n * DIM + ko);
            Bl[kc] = *reinterpret_cast<const bfrag*>(mkT_lo + n * DIM + ko);
        }

        f32x4 acc[4];
        #pragma unroll
        for (int t = 0; t < 4; ++t) acc[t] = 0.f;

        #pragma unroll
        for (int rt = 0; rt < 4; ++rt) {
            #pragma unroll
            for (int kc = 0; kc < 4; ++kc) {
                const int ko = kc * 32 + quad * 8;
                bfrag Ah = *reinterpret_cast<const bfrag*>(&shi[rt][nloc][ko]);
                acc[rt] = __builtin_amdgcn_mfma_f32_16x16x32_bf16(Ah, Bh[kc], acc[rt], 0, 0, 0);
                acc[rt] = __builtin_amdgcn_mfma_f32_16x16x32_bf16(Ah, Bl[kc], acc[rt], 0, 0, 0);
            }
        }

        float ex[4][4];
        #pragma unroll
        for (int rt = 0; rt < 4; ++rt) {
            #pragma unroll
            for (int rg = 0; rg < 4; ++rg) {
                float e = __expf(acc[rt][rg]);
                ex[rt][rg] = e;
                float s = e;
                s += __shfl_xor(s, 1);
                s += __shfl_xor(s, 2);
                s += __shfl_xor(s, 4);
                s += __shfl_xor(s, 8);
                if (nloc == 0) slab[wv][rt * 16 + quad * 4 + rg] = s;
            }
        }
        __syncthreads();

        #pragma unroll
        for (int rt = 0; rt < 4; ++rt) {
            #pragma unroll
            for (int rg = 0; rg < 4; ++rg) {
                const int row = rt * 16 + quad * 4 + rg;
                float tot = slab[0][row] + slab[1][row] + slab[2][row] + slab[3][row];
                w_out[(size_t)(base + row) * MM + n] = ex[rt][rg] / tot;
            }
        }
    } else {
        // ---------------- kB role ----------------
        const int base = (blockIdx.x - 512) * 64;
        {   // stage v = evbf[x] (already bf16)
            const int row_l = tid >> 2;
            const int rts = row_l >> 4, ms = row_l & 15;
            const int d0 = (tid & 3) * 32;
            const int row = base + row_l;
            const int x = q[row] + NUM_C * r[row];
            const u16* src = evbf + (size_t)x * DIM + d0;
            #pragma unroll
            for (int c8 = 0; c8 < 4; ++c8)
                *reinterpret_cast<bfrag*>(&shi[rts][ms][d0 + c8 * 8]) =
                    *reinterpret_cast<const bfrag*>(src + c8 * 8);
        }
        __syncthreads();

        #pragma unroll
        for (int dt = 0; dt < 2; ++dt) {
            const int n = (wv * 2 + dt) * 16 + nloc;
            bfrag Beh[4], Bel[4], Bah[4], Bal[4];
            #pragma unroll
            for (int kc = 0; kc < 4; ++kc) {
                const int ko = kc * 32 + quad * 8;
                Beh[kc] = *reinterpret_cast<const bfrag*>(weT_hi + n * DIM + ko);
                Bel[kc] = *reinterpret_cast<const bfrag*>(weT_lo + n * DIM + ko);
                Bah[kc] = *reinterpret_cast<const bfrag*>(waT_hi + n * DIM + ko);
                Bal[kc] = *reinterpret_cast<const bfrag*>(waT_lo + n * DIM + ko);
            }
            f32x4 acc_e[4], acc_a[4];
            #pragma unroll
            for (int t = 0; t < 4; ++t) { acc_e[t] = 0.f; acc_a[t] = 0.f; }

            #pragma unroll
            for (int rt = 0; rt < 4; ++rt) {
                #pragma unroll
                for (int kc = 0; kc < 4; ++kc) {
                    const int ko = kc * 32 + quad * 8;
                    bfrag Ah = *reinterpret_cast<const bfrag*>(&shi[rt][nloc][ko]);
                    acc_e[rt] = __builtin_amdgcn_mfma_f32_16x16x32_bf16(Ah, Beh[kc], acc_e[rt], 0, 0, 0);
                    acc_a[rt] = __builtin_amdgcn_mfma_f32_16x16x32_bf16(Ah, Bah[kc], acc_a[rt], 0, 0, 0);
                    acc_e[rt] = __builtin_amdgcn_mfma_f32_16x16x32_bf16(Ah, Bel[kc], acc_e[rt], 0, 0, 0);
                    acc_a[rt] = __builtin_amdgcn_mfma_f32_16x16x32_bf16(Ah, Bal[kc], acc_a[rt], 0, 0, 0);
                }
            }
            const float bev = be[n], bav = ba[n];
            #pragma unroll
            for (int rt = 0; rt < 4; ++rt) {
                #pragma unroll
                for (int rg = 0; rg < 4; ++rg) {
                    const int row = base + rt * 16 + quad * 4 + rg;
                    float2 ea;
                    ea.x = sigmoidf_fast(acc_e[rt][rg] + bev);
                    ea.y = tanhf_fast(acc_a[rt][rg] + bav);
                    ea_out[(size_t)row * DIM + n] = ea;
                }
            }
        }
    }
}

// ---------------------------------------------------------------------------
// Kernel C (unchanged from r14): async-DMA LDS tiles, full in-wave m-reduce.
// ---------------------------------------------------------------------------
__device__ __forceinline__ void scan32(const float* wb, const float2* eab,
                                       int m0, int dl, int p, int t0,
                                       float (&Mv)[4], float* rp) {
    #pragma unroll
    for (int u = 0; u < 32; ++u) {
        float4 w4 = *reinterpret_cast<const float4*>(wb + u * 64 + m0);
        float2 ea = eab[u * 32 + dl];
        float wv[4] = {w4.x, w4.y, w4.z, w4.w};
        float e_c = ea.x, a_c = ea.y;
        float part = 0.f;
        #pragma unroll
        for (int j = 0; j < 4; ++j) {
            float old = Mv[j];
            part = fmaf(wv[j], old, part);                   // read BEFORE update
            Mv[j] = fmaf(wv[j], fmaf(-old, e_c, a_c), old);
        }
        part += quad_swap1(part);
        part += quad_swap2(part);
        part += row_ror4(part);
        part += row_ror8(part);       // full 16-lane (64-m) sum
        if (p == 0) rp[(size_t)(t0 + u) * DIM] = part;
    }
}

__global__ __launch_bounds__(512) void kC(const float* __restrict__ Mv0,
                                          const float* __restrict__ w_in,
                                          const float2* __restrict__ ea_in,
                                          float* __restrict__ rd) {
    __shared__ __align__(16) float  wlds[2][32][64];    // 16 KB
    __shared__ __align__(16) float2 ealds[2][32][32];   // 16 KB
    const int tid = threadIdx.x;
    const int lane = tid & 63;
    const int wvid = tid >> 6;        // 0..7
    const int p = tid & 15;
    const int dl = tid >> 4;          // 0..31
    const int ds = blockIdx.x, b = blockIdx.y;
    const int d = ds * 32 + dl;
    const int m0 = p * 4;

    const char* wsrc  = (const char*)(w_in + (size_t)b * LL * MM);
    const char* easrc = (const char*)(ea_in + (size_t)b * LL * DIM + ds * 32);
    float* rp = rd + (size_t)b * LL * DIM + d;

    auto dma = [&](int c, int bufi) {
        const char* wt = wsrc + (size_t)c * 8192;
        char* wl = (char*)&wlds[bufi][0][0];
        char* el = (char*)&ealds[bufi][0][0];
        const int off = wvid * 1024 + lane * 16;          // 0..8191
        ld16(wt + off, wl + off);                         // w: contiguous 8 KB
        const int tl = off >> 8, wi = off & 255;          // ea: 256B rows, 1KB stride
        ld16(easrc + (size_t)(c * 32 + tl) * (DIM * 8) + wi, el + off);
    };

    dma(0, 0);

    float Mv[4];
    #pragma unroll
    for (int j = 0; j < 4; ++j)
        Mv[j] = Mv0[(m0 + j) * DIM + d];

    __builtin_amdgcn_s_waitcnt(0x0F70);   // vmcnt(0): tile-0 DMA + Mv loads done
    __syncthreads();

    int buf = 0;
    for (int c = 0; c < LL / 32; ++c) {
        if (c + 1 < LL / 32) dma(c + 1, buf ^ 1);
        scan32(&wlds[buf][0][0], &ealds[buf][0][0], m0, dl, p, c * 32, Mv, rp);
        if (c + 1 < LL / 32) {
            __builtin_amdgcn_s_waitcnt(0x8F70);   // vmcnt(32): DMAs retired, stores may fly
            __syncthreads();
            buf ^= 1;
        }
    }
}

// ---------------------------------------------------------------------------
// Kernel D (MFMA, A=hi only): f = tanh([rd,k]@Wf+bf); p = sigmoid(f@Wp+bp).
// 64 rows/block; rd staged via f2bf (hi), Ek gathered pre-converted.
// ---------------------------------------------------------------------------
__global__ __launch_bounds__(256) void kD(const int* __restrict__ q,
                                          const u16* __restrict__ ekbf,
                                          const u16* __restrict__ wfT_hi, const u16* __restrict__ wfT_lo,
                                          const float* __restrict__ bfv,
                                          const float* __restrict__ Wp, const float* __restrict__ bp,
                                          const float* __restrict__ rd,
                                          float* __restrict__ out) {
    __shared__ __align__(16) u16 xhi[4][16][264];   // 33792 B (fbuf overlays exactly)
    __shared__ float sred[64][4];
    const int tid = threadIdx.x;
    const int base = blockIdx.x * 64;
    const int row_l = tid >> 2;
    const int rts = row_l >> 4, ms = row_l & 15;
    const int d0 = (tid & 3) * 32;
    const int row = base + row_l;

    {   // x[:, 0:128) = rd -> bf16 hi
        const float* src = rd + (size_t)row * DIM + d0;
        #pragma unroll
        for (int c8 = 0; c8 < 4; ++c8) {
            float4 f0 = *reinterpret_cast<const float4*>(src + c8 * 8);
            float4 f1 = *reinterpret_cast<const float4*>(src + c8 * 8 + 4);
            float xs[8] = {f0.x, f0.y, f0.z, f0.w, f1.x, f1.y, f1.z, f1.w};
            bfrag h;
            #pragma unroll
            for (int j = 0; j < 8; ++j) h[j] = (short)f2bf(xs[j]);
            *reinterpret_cast<bfrag*>(&xhi[rts][ms][d0 + c8 * 8]) = h;
        }
    }
    {   // x[:, 128:256) = ekbf[q[row]] (already bf16)
        const u16* src = ekbf + (size_t)q[row] * DIM + d0;
        #pragma unroll
        for (int c8 = 0; c8 < 4; ++c8)
            *reinterpret_cast<bfrag*>(&xhi[rts][ms][128 + d0 + c8 * 8]) =
                *reinterpret_cast<const bfrag*>(src + c8 * 8);
    }
    __syncthreads();

    const int lane = tid & 63;
    const int wv = tid >> 6;
    const int nloc = lane & 15;
    const int quad = lane >> 4;
    float* fbuf = reinterpret_cast<float*>(&xhi[0][0][0]);   // overlay after sync

    f32x4 acc[2][4];
    #pragma unroll
    for (int dt = 0; dt < 2; ++dt)
        #pragma unroll
        for (int t = 0; t < 4; ++t) acc[dt][t] = 0.f;

    #pragma unroll
    for (int dt = 0; dt < 2; ++dt) {
        const int n = (wv * 2 + dt) * 16 + nloc;
        bfrag Bh[8], Bl[8];
        #pragma unroll
        for (int kc = 0; kc < 8; ++kc) {
            const int ko = kc * 32 + quad * 8;
            Bh[kc] = *reinterpret_cast<const bfrag*>(wfT_hi + n * 256 + ko);
            Bl[kc] = *reinterpret_cast<const bfrag*>(wfT_lo + n * 256 + ko);
        }
        #pragma unroll
        for (int rt = 0; rt < 4; ++rt) {
            #pragma unroll
            for (int kc = 0; kc < 8; ++kc) {
                const int ko = kc * 32 + quad * 8;
                bfrag Ah = *reinterpret_cast<const bfrag*>(&xhi[rt][nloc][ko]);
                acc[dt][rt] = __builtin_amdgcn_mfma_f32_16x16x32_bf16(Ah, Bh[kc], acc[dt][rt], 0, 0, 0);
                acc[dt][rt] = __builtin_amdgcn_mfma_f32_16x16x32_bf16(Ah, Bl[kc], acc[dt][rt], 0, 0, 0);
            }
        }
    }
    __syncthreads();   // LDS x reads done before fbuf overlay

    #pragma unroll
    for (int dt = 0; dt < 2; ++dt) {
        const int n = (wv * 2 + dt) * 16 + nloc;
        const float bfn = bfv[n], wpn = Wp[n];
        #pragma unroll
        for (int rt = 0; rt < 4; ++rt)
            #pragma unroll
            for (int rg = 0; rg < 4; ++rg)
                fbuf[(rt * 16 + quad * 4 + rg) * 132 + n] = tanhf_fast(acc[dt][rt][rg] + bfn) * wpn;
    }
    __syncthreads();

    {
        float s = 0.f;
        const int c = tid & 3;
        #pragma unroll
        for (int k = 0; k < 32; ++k) s += fbuf[row_l * 132 + c * 32 + k];
        sred[row_l][c] = s;
    }
    __syncthreads();
    if (tid < 64)
        out[base + tid] = sigmoidf_fast(sred[tid][0] + sred[tid][1] + sred[tid][2] + sred[tid][3] + bp[0]);
}

// ---------------------------------------------------------------------------
extern "C" void kernel_launch(void* const* d_in, const int* in_sizes, int n_in,
                              void* d_out, int out_size, void* d_ws, size_t ws_size,
                              hipStream_t stream) {
    const int*   q   = (const int*)d_in[0];
    const int*   r   = (const int*)d_in[1];
    const float* Ek  = (const float*)d_in[2];
    const float* Ev  = (const float*)d_in[3];
    const float* Mk  = (const float*)d_in[4];
    const float* Mv0 = (const float*)d_in[5];
    const float* We  = (const float*)d_in[6];
    const float* be  = (const float*)d_in[7];
    const float* Wa  = (const float*)d_in[8];
    const float* ba  = (const float*)d_in[9];
    const float* Wf  = (const float*)d_in[10];
    const float* bfv = (const float*)d_in[11];
    const float* Wp  = (const float*)d_in[12];
    const float* bp  = (const float*)d_in[13];
    float* out = (float*)d_out;

    float*  ws     = (float*)d_ws;
    float*  w_buf  = ws;                                      // 8 MB
    float2* ea_buf = (float2*)(w_buf + (size_t)NROWS * MM);   // 32 MB
    float*  rd     = (float*)(ea_buf + (size_t)NROWS * DIM);  // 16 MB

    // prepped bf16 data right after rd (~1.1 MB)
    u16* weT_hi = (u16*)(rd + (size_t)NROWS * DIM);
    u16* weT_lo = weT_hi + 16384;
    u16* waT_hi = weT_lo + 16384;
    u16* waT_lo = waT_hi + 16384;
    u16* wfT_hi = waT_lo + 16384;
    u16* wfT_lo = wfT_hi + 32768;
    u16* mkT_hi = wfT_lo + 32768;
    u16* mkT_lo = mkT_hi + 8192;
    u16* ekbf   = mkT_lo + 8192;      // 128000 u16
    u16* evbf   = ekbf + 128000;      // 256000 u16

    kP<<<dim3(128), 256, 0, stream>>>(We, Wa, Wf, Mk, Ek, Ev,
                                      weT_hi, weT_lo, waT_hi, waT_lo,
                                      wfT_hi, wfT_lo, mkT_hi, mkT_lo, ekbf, evbf);
    kAB<<<dim3(1024), 256, 0, stream>>>(q, r, ekbf, evbf, mkT_hi, mkT_lo,
                                        weT_hi, weT_lo, waT_hi, waT_lo,
                                        be, ba, w_buf, ea_buf);
    kC<<<dim3(4, BB), 512, 0, stream>>>(Mv0, w_buf, ea_buf, rd);
    kD<<<dim3(NROWS / 64), 256, 0, stream>>>(q, ekbf, wfT_hi, wfT_lo, bfv, Wp, bp, rd, out);
}